// Round 5
// baseline (27482.361 us; speedup 1.0000x reference)
//
#include <hip/hip_runtime.h>

#define Lnum 2
#define BSn  64
#define Tn   512
#define ECn  1024
#define CA1n 1024
#define CHUNK 16

typedef short bf16x8 __attribute__((ext_vector_type(8)));
typedef float f32x4  __attribute__((ext_vector_type(4)));

#define MFMA16(a,b,c) __builtin_amdgcn_mfma_f32_16x16x32_bf16((a),(b),(c),0,0,0)

// d_out layout: [actCell 64*2][ec3his 2*512*1024][ec5his ...][ca1his ...]
#define OUT_E3  128
#define OUT_E5  (128 + Lnum*Tn*ECn)
#define OUT_CA1 (128 + 2*Lnum*Tn*ECn)

// ws layout (bytes)
#define WS_FLAGS 0                      // 128 flags * 64B
#define WS_EC3U  8192                   // u32 [2][64][512] packed bf16 pairs
#define WS_CA1U  270336                 // u32 [2][64][512]
#define WS_EC5F  532480                 // f32 [2][64][1024]
#define WS_EC3F  1056768                // f32 [2][64][1024]
#define WS_CA1L  1581056                // f32 [64][1024]
#define WS_S     1843200                // bf16 [2][512][1024]
#define WS_W1T   3940352                // bf16 [2][1024c][1024k]
#define WS_W2T   8134656                // bf16 [2][1024e][1024k]
#define WS_W3T   12328960               // bf16 [1024e][1024k]

#define AST(p, v) __hip_atomic_store((p), (v), __ATOMIC_RELAXED, __HIP_MEMORY_SCOPE_AGENT)
#define ALD(p)    __hip_atomic_load((p), __ATOMIC_RELAXED, __HIP_MEMORY_SCOPE_AGENT)

__device__ __forceinline__ float sigm(float x) { return 1.0f / (1.0f + __expf(-x)); }

__device__ __forceinline__ unsigned f2bfu(float f) {
  unsigned u = __float_as_uint(f);
  u += 0x7fffu + ((u >> 16) & 1u);   // RNE
  return u >> 16;
}
__device__ __forceinline__ short f2bf(float f) { return (short)f2bfu(f); }
__device__ __forceinline__ float bf2f(short s) {
  return __uint_as_float(((unsigned)(unsigned short)s) << 16);
}

// coherence-point 16B A-fragment load as 4 relaxed agent-scope dword atomics
__device__ __forceinline__ bf16x8 loadA(const unsigned* p) {
  union { unsigned u[4]; bf16x8 b; } x;
  unsigned* q = (unsigned*)p;
  x.u[0] = ALD(q + 0);
  x.u[1] = ALD(q + 1);
  x.u[2] = ALD(q + 2);
  x.u[3] = ALD(q + 3);
  return x.b;
}

// ---------------- prep kernels (R4-proven) ----------------

__global__ void prep_state(const float* __restrict__ ec3_last,
                           const float* __restrict__ ec5_last,
                           unsigned* __restrict__ flags, unsigned* __restrict__ ec3u,
                           float* __restrict__ ec5f, float* __restrict__ ec3f) {
  int i = blockIdx.x * blockDim.x + threadIdx.x;   // 512*256 = 131072
  if (i < 2048) flags[i] = 0u;
  float v3 = ec3_last[i];
  ec3f[i] = v3;
  ec5f[i] = ec5_last[i];
  if (i < Lnum * BSn * 512) {
    float lo = ec3_last[2 * i], hi = ec3_last[2 * i + 1];
    ec3u[i] = f2bfu(lo) | (f2bfu(hi) << 16);
  }
}

// 64x64 LDS tile transpose fp32[k][c] -> bf16[c][k], for W1 (m=0) and W2 (m=1)
__global__ void prep_wt(const float* __restrict__ w1, const float* __restrict__ w2,
                        short* __restrict__ w1t, short* __restrict__ w2t) {
  __shared__ float tile[64][65];
  const int b = blockIdx.x;               // 1024 = 2 mats * 2 layers * 16*16 tiles
  const int m  = b >> 9;
  const int li = (b >> 8) & 1;
  const int kt = (b >> 4) & 15;
  const int ct = b & 15;
  const float* src = (m == 0 ? w1 : w2) + li * (1024 * 1024);
  short* dst = (m == 0 ? w1t : w2t) + li * (1024 * 1024);
#pragma unroll
  for (int i = 0; i < 16; ++i) {
    int idx = threadIdx.x + i * 256;
    int r = idx >> 6, c = idx & 63;
    tile[r][c] = src[(kt * 64 + r) * 1024 + ct * 64 + c];
  }
  __syncthreads();
#pragma unroll
  for (int i = 0; i < 16; ++i) {
    int idx = threadIdx.x + i * 256;
    int c = idx >> 6, r = idx & 63;
    dst[(ct * 64 + c) * 1024 + kt * 64 + r] = f2bf(tile[r][c]);
  }
}

__global__ void prep_w3(const float* __restrict__ inter_w, short* __restrict__ w3t) {
  int i = blockIdx.x * blockDim.x + threadIdx.x;   // 4096*256 = 1048576
  w3t[i] = f2bf(inter_w[i]);                        // layer 0, already [e][k]
}

__global__ void prep_ca3(const float* __restrict__ wca3ca1, short* __restrict__ S) {
  const int t = blockIdx.x >> 1, li = blockIdx.x & 1;
  __shared__ float gauss[192];
  const float stepc = 512.0f / 1023.0f;
  const float tf = (float)t;
  int kmin = (int)floorf((tf - 40.0f) / stepc) - 1; if (kmin < 0) kmin = 0;
  int kmax = (int)ceilf((tf + 40.0f) / stepc) + 1;  if (kmax > 1023) kmax = 1023;
  int nw = kmax - kmin + 1;
  for (int j = threadIdx.x; j < nw; j += 256) {
    float d = (float)(kmin + j) * stepc - tf;
    gauss[j] = __expf(-d * d * 0.02f);
  }
  __syncthreads();
  const float* W = wca3ca1 + li * (1024 * 1024);
  for (int c = threadIdx.x; c < 1024; c += 256) {
    float s = 0.0f;
    for (int j = 0; j < nw; ++j) s += gauss[j] * W[(kmin + j) * 1024 + c];
    S[(li * Tn + t) * 1024 + c] = f2bf(sigm(10.0f * (s - 0.5f)));
  }
}

// ---- flag-array grid barrier (128 blocks; fence-free: shared data is agent-atomic)
__device__ __forceinline__ void gridbar(unsigned* flags, unsigned target) {
  asm volatile("s_waitcnt vmcnt(0)" ::: "memory");  // own stores acked at coherence pt
  __syncthreads();                                  // => all waves' stores acked
  if (threadIdx.x == 0) AST(&flags[blockIdx.x * 16], target);
  if (threadIdx.x < 128) {
    while (ALD(&flags[threadIdx.x * 16]) < target) {}
  }
  __builtin_amdgcn_sched_barrier(0);
  __syncthreads();
}

// ---------------- 16-step chunk kernel ----------------
// grid 128 = [li:1][ctile:6], block 256 = 4 waves; wave w -> rows w*16..w*16+15
__global__ void __launch_bounds__(256, 1) stepchunk(
    const float* __restrict__ cue,
    const short* __restrict__ w1t, const short* __restrict__ w2t,
    const short* __restrict__ w3t, const short* __restrict__ stab,
    const float* __restrict__ ca1bias, const float* __restrict__ ec5bias,
    const float* __restrict__ interb,
    unsigned* __restrict__ flags, unsigned* __restrict__ ec3u,
    unsigned* __restrict__ ca1u, float* __restrict__ ec5f, float* __restrict__ ec3f,
    float* __restrict__ ca1l, float* __restrict__ out, int t0, int base) {
  const int b = blockIdx.x;
  const int li = b >> 6;
  const int c0 = (b & 63) << 4;
  const int tid = threadIdx.x;
  const int lane = tid & 63, wave = tid >> 6;
  const int fr = lane & 15, ks = lane >> 4;
  const int r0 = wave << 4;
  const int ccol = c0 + fr;

  const unsigned* A1u = ec3u + li * 32768 + (r0 + fr) * 512 + ks * 4;
  const unsigned* A2u = ca1u + li * 32768 + (r0 + fr) * 512 + ks * 4;
  const unsigned* A3u = ca1u + (r0 + fr) * 512 + ks * 4;          // layer-0 ca1
  const short* B1 = w1t + li * 1048576 + ccol * 1024 + ks * 8;
  const short* B2 = w2t + li * 1048576 + ccol * 1024 + ks * 8;
  const short* B3 = w3t + ccol * 1024 + ks * 8;

  const float cb  = ca1bias[li * 1024 + ccol];
  const float e5b = ec5bias[li * 1024 + ccol];
  const float ib0 = interb[1024 + ccol];    // layer-1 inter_b (used when li==1)

  // block-exclusive fp32 state -> registers for the chunk
  float e5r[4], e3r[4];
#pragma unroll
  for (int r = 0; r < 4; ++r) {
    int sidx = li * 65536 + (r0 + ks * 4 + r) * 1024 + ccol;
    e5r[r] = ec5f[sidx];
    e3r[r] = ec3f[sidx];
  }

  unsigned tgt = (unsigned)base;

  for (int tt = 0; tt < CHUNK; ++tt) {
    const int t = t0 + tt;

    float cueq[4];
    if (li == 0) {                        // prefetch cue for phase B
#pragma unroll
      for (int r = 0; r < 4; ++r)
        cueq[r] = cue[((r0 + ks * 4 + r) * Tn + t) * 1024 + ccol];
    }

    // ---------- phase A: ca1 = relu(S * (1 + 3*sig(ec3@W1)) - bias) ----------
    {
      f32x4 a0 = {0.f,0.f,0.f,0.f}, a1 = {0.f,0.f,0.f,0.f};
#pragma unroll
      for (int kk = 0; kk < 16; ++kk) {
        a0 = MFMA16(loadA(A1u + kk * 16),       *(const bf16x8*)(B1 + kk * 32),       a0);
        a1 = MFMA16(loadA(A1u + 256 + kk * 16), *(const bf16x8*)(B1 + 512 + kk * 32), a1);
      }
      f32x4 acc = a0 + a1;
      const float g = bf2f(stab[(li * Tn + t) * 1024 + ccol]);
#pragma unroll
      for (int r = 0; r < 4; ++r) {
        int grow = r0 + ks * 4 + r;
        float cv = fmaxf(g * (1.0f + 3.0f * sigm(acc[r])) - cb, 0.0f);
        unsigned my = f2bfu(cv);
        unsigned pr = (unsigned)__shfl_xor((int)my, 1);
        if ((fr & 1) == 0)
          AST(ca1u + li * 32768 + grow * 512 + ((c0 + fr) >> 1), my | (pr << 16));
        if (grow == 0) out[OUT_CA1 + (li * Tn + t) * 1024 + ccol] = cv;
        if (t == Tn - 1 && li == 1) ca1l[grow * 1024 + ccol] = cv;
      }
    }
    gridbar(flags, ++tgt);

    // ---------- phase B: ec5/ec3 update ----------
    {
      f32x4 p0 = {0.f,0.f,0.f,0.f}, p1 = {0.f,0.f,0.f,0.f};
#pragma unroll
      for (int kk = 0; kk < 16; ++kk) {
        p0 = MFMA16(loadA(A2u + kk * 16),       *(const bf16x8*)(B2 + kk * 32),       p0);
        p1 = MFMA16(loadA(A2u + 256 + kk * 16), *(const bf16x8*)(B2 + 512 + kk * 32), p1);
      }
      f32x4 g2 = p0 + p1;

      f32x4 xin;
      if (li == 1) {
        f32x4 q0 = {0.f,0.f,0.f,0.f}, q1 = {0.f,0.f,0.f,0.f};
#pragma unroll
        for (int kk = 0; kk < 16; ++kk) {
          q0 = MFMA16(loadA(A3u + kk * 16),       *(const bf16x8*)(B3 + kk * 32),       q0);
          q1 = MFMA16(loadA(A3u + 256 + kk * 16), *(const bf16x8*)(B3 + 512 + kk * 32), q1);
        }
        f32x4 q = q0 + q1;
#pragma unroll
        for (int r = 0; r < 4; ++r) xin[r] = q[r] + ib0;
      } else {
#pragma unroll
        for (int r = 0; r < 4; ++r) xin[r] = cueq[r];
      }

#pragma unroll
      for (int r = 0; r < 4; ++r) {
        int grow = r0 + ks * 4 + r;
        float raw = e5r[r] + g2[r] + e5b;            // 10*TS == 1.0f exactly
        float e5 = 0.69f + 0.3f * sigm(4.0f * (raw - 0.3f));
        e5r[r] = e5;
        float e3 = e5 * e3r[r] + 0.6f * xin[r];
        e3r[r] = e3;
        unsigned my = f2bfu(e3);
        unsigned pr = (unsigned)__shfl_xor((int)my, 1);
        if ((fr & 1) == 0)
          AST(ec3u + li * 32768 + grow * 512 + ((c0 + fr) >> 1), my | (pr << 16));
        if (grow == 0) {
          out[OUT_E5 + (li * Tn + t) * 1024 + ccol] = e5;
          out[OUT_E3 + (li * Tn + t) * 1024 + ccol] = e3;
        }
      }
    }
    gridbar(flags, ++tgt);
  }

  // spill fp32 state for next chunk (dispatch boundary provides coherence)
#pragma unroll
  for (int r = 0; r < 4; ++r) {
    int sidx = li * 65536 + (r0 + ks * 4 + r) * 1024 + ccol;
    ec5f[sidx] = e5r[r];
    ec3f[sidx] = e3r[r];
  }
}

__global__ void act_cell(const float* __restrict__ ca1l, const float* __restrict__ wca1act,
                         const float* __restrict__ actbias, float* __restrict__ out) {
  int tid = threadIdx.x;
  if (tid < 128) {
    int b = tid >> 1, a = tid & 1;
    float s = 0.0f;
    for (int k = 0; k < 1024; ++k) s += ca1l[b * 1024 + k] * wca1act[k * 2 + a];
    out[b * 2 + a] = s + actbias[a];
  }
}

extern "C" void kernel_launch(void* const* d_in, const int* in_sizes, int n_in,
                              void* d_out, int out_size, void* d_ws, size_t ws_size,
                              hipStream_t stream) {
  (void)in_sizes; (void)n_in; (void)out_size; (void)ws_size;
  const float* cue      = (const float*)d_in[0];
  const float* ec3_last = (const float*)d_in[1];
  const float* ec5_last = (const float*)d_in[2];
  const float* wca3ca1  = (const float*)d_in[4];
  const float* wec3ca1  = (const float*)d_in[5];
  const float* wca1ec5  = (const float*)d_in[6];
  const float* ca1bias  = (const float*)d_in[7];
  const float* ec5bias  = (const float*)d_in[8];
  const float* inter_w  = (const float*)d_in[9];
  const float* inter_b  = (const float*)d_in[10];
  const float* wca1act  = (const float*)d_in[11];
  const float* actbias  = (const float*)d_in[12];
  float* out = (float*)d_out;

  char* ws = (char*)d_ws;
  unsigned* flags = (unsigned*)(ws + WS_FLAGS);
  unsigned* ec3u  = (unsigned*)(ws + WS_EC3U);
  unsigned* ca1u  = (unsigned*)(ws + WS_CA1U);
  float* ec5f = (float*)(ws + WS_EC5F);
  float* ec3f = (float*)(ws + WS_EC3F);
  float* ca1l = (float*)(ws + WS_CA1L);
  short* stab = (short*)(ws + WS_S);
  short* w1t  = (short*)(ws + WS_W1T);
  short* w2t  = (short*)(ws + WS_W2T);
  short* w3t  = (short*)(ws + WS_W3T);

  prep_state<<<dim3(512), dim3(256), 0, stream>>>(ec3_last, ec5_last, flags, ec3u, ec5f, ec3f);
  prep_wt<<<dim3(1024), dim3(256), 0, stream>>>(wec3ca1, wca1ec5, w1t, w2t);
  prep_w3<<<dim3(4096), dim3(256), 0, stream>>>(inter_w, w3t);
  prep_ca3<<<dim3(1024), dim3(256), 0, stream>>>(wca3ca1, stab);

  for (int c = 0; c < Tn / CHUNK; ++c) {
    stepchunk<<<dim3(128), dim3(256), 0, stream>>>(
        cue, w1t, w2t, w3t, stab, ca1bias, ec5bias, inter_b,
        flags, ec3u, ca1u, ec5f, ec3f, ca1l, out, c * CHUNK, c * 2 * CHUNK);
  }

  act_cell<<<dim3(1), dim3(128), 0, stream>>>(ca1l, wca1act, actbias, out);
}

// Round 6
// 23825.447 us; speedup vs baseline: 1.1535x; 1.1535x over previous
//
#include <hip/hip_runtime.h>

#define Lnum 2
#define BSn  64
#define Tn   512
#define ECn  1024
#define CA1n 1024
#define CHUNK 16

typedef short bf16x8 __attribute__((ext_vector_type(8)));
typedef float f32x4  __attribute__((ext_vector_type(4)));

#define MFMA16(a,b,c) __builtin_amdgcn_mfma_f32_16x16x32_bf16((a),(b),(c),0,0,0)

// d_out layout: [actCell 64*2][ec3his 2*512*1024][ec5his ...][ca1his ...]
#define OUT_E3  128
#define OUT_E5  (128 + Lnum*Tn*ECn)
#define OUT_CA1 (128 + 2*Lnum*Tn*ECn)

// ws layout (bytes)
#define WS_FLAGS 0                      // 128 flags * 64B
#define WS_EC3U  8192                   // u32 [2][64][512] packed bf16 pairs
#define WS_CA1U  270336                 // u32 [2][64][512]
#define WS_EC5F  532480                 // f32 [2][64][1024]
#define WS_EC3F  1056768                // f32 [2][64][1024]
#define WS_CA1L  1581056                // f32 [64][1024]
#define WS_S     1843200                // bf16 [2][512][1024]
#define WS_W1T   3940352                // bf16 [2][1024c][1024k]
#define WS_W2T   8134656                // bf16 [2][1024e][1024k]
#define WS_W3T   12328960               // bf16 [1024e][1024k]

#define AST(p, v) __hip_atomic_store((p), (v), __ATOMIC_RELAXED, __HIP_MEMORY_SCOPE_AGENT)
#define ALD(p)    __hip_atomic_load((p), __ATOMIC_RELAXED, __HIP_MEMORY_SCOPE_AGENT)

__device__ __forceinline__ float sigm(float x) { return 1.0f / (1.0f + __expf(-x)); }

__device__ __forceinline__ unsigned f2bfu(float f) {
  unsigned u = __float_as_uint(f);
  u += 0x7fffu + ((u >> 16) & 1u);   // RNE
  return u >> 16;
}
__device__ __forceinline__ short f2bf(float f) { return (short)f2bfu(f); }
__device__ __forceinline__ float bf2f(short s) {
  return __uint_as_float(((unsigned)(unsigned short)s) << 16);
}

// coherence-point 16B A-fragment load as 4 relaxed agent-scope dword atomics
__device__ __forceinline__ bf16x8 loadA(const unsigned* p) {
  union { unsigned u[4]; bf16x8 b; } x;
  unsigned* q = (unsigned*)p;
  x.u[0] = ALD(q + 0);
  x.u[1] = ALD(q + 1);
  x.u[2] = ALD(q + 2);
  x.u[3] = ALD(q + 3);
  return x.b;
}

// ---------------- prep kernels (R4/R5-proven) ----------------

__global__ void prep_state(const float* __restrict__ ec3_last,
                           const float* __restrict__ ec5_last,
                           unsigned* __restrict__ flags, unsigned* __restrict__ ec3u,
                           float* __restrict__ ec5f, float* __restrict__ ec3f) {
  int i = blockIdx.x * blockDim.x + threadIdx.x;   // 512*256 = 131072
  if (i < 2048) flags[i] = 0u;
  float v3 = ec3_last[i];
  ec3f[i] = v3;
  ec5f[i] = ec5_last[i];
  if (i < Lnum * BSn * 512) {
    float lo = ec3_last[2 * i], hi = ec3_last[2 * i + 1];
    ec3u[i] = f2bfu(lo) | (f2bfu(hi) << 16);
  }
}

// 64x64 LDS tile transpose fp32[k][c] -> bf16[c][k], for W1 (m=0) and W2 (m=1)
__global__ void prep_wt(const float* __restrict__ w1, const float* __restrict__ w2,
                        short* __restrict__ w1t, short* __restrict__ w2t) {
  __shared__ float tile[64][65];
  const int b = blockIdx.x;               // 1024 = 2 mats * 2 layers * 16*16 tiles
  const int m  = b >> 9;
  const int li = (b >> 8) & 1;
  const int kt = (b >> 4) & 15;
  const int ct = b & 15;
  const float* src = (m == 0 ? w1 : w2) + li * (1024 * 1024);
  short* dst = (m == 0 ? w1t : w2t) + li * (1024 * 1024);
#pragma unroll
  for (int i = 0; i < 16; ++i) {
    int idx = threadIdx.x + i * 256;
    int r = idx >> 6, c = idx & 63;
    tile[r][c] = src[(kt * 64 + r) * 1024 + ct * 64 + c];
  }
  __syncthreads();
#pragma unroll
  for (int i = 0; i < 16; ++i) {
    int idx = threadIdx.x + i * 256;
    int c = idx >> 6, r = idx & 63;
    dst[(ct * 64 + c) * 1024 + kt * 64 + r] = f2bf(tile[r][c]);
  }
}

__global__ void prep_w3(const float* __restrict__ inter_w, short* __restrict__ w3t) {
  int i = blockIdx.x * blockDim.x + threadIdx.x;   // 4096*256 = 1048576
  w3t[i] = f2bf(inter_w[i]);                        // layer 0, already [e][k]
}

__global__ void prep_ca3(const float* __restrict__ wca3ca1, short* __restrict__ S) {
  const int t = blockIdx.x >> 1, li = blockIdx.x & 1;
  __shared__ float gauss[192];
  const float stepc = 512.0f / 1023.0f;
  const float tf = (float)t;
  int kmin = (int)floorf((tf - 40.0f) / stepc) - 1; if (kmin < 0) kmin = 0;
  int kmax = (int)ceilf((tf + 40.0f) / stepc) + 1;  if (kmax > 1023) kmax = 1023;
  int nw = kmax - kmin + 1;
  for (int j = threadIdx.x; j < nw; j += 256) {
    float d = (float)(kmin + j) * stepc - tf;
    gauss[j] = __expf(-d * d * 0.02f);
  }
  __syncthreads();
  const float* W = wca3ca1 + li * (1024 * 1024);
  for (int c = threadIdx.x; c < 1024; c += 256) {
    float s = 0.0f;
    for (int j = 0; j < nw; ++j) s += gauss[j] * W[(kmin + j) * 1024 + c];
    S[(li * Tn + t) * 1024 + c] = f2bf(sigm(10.0f * (s - 0.5f)));
  }
}

// ---- flag-array grid barrier (128 blocks; fence-free: shared data is agent-atomic)
__device__ __forceinline__ void gridbar(unsigned* flags, unsigned target) {
  asm volatile("s_waitcnt vmcnt(0)" ::: "memory");  // own stores acked at coherence pt
  __syncthreads();                                  // => all waves' stores acked
  if (threadIdx.x == 0) AST(&flags[blockIdx.x * 16], target);
  if (threadIdx.x < 128) {
    while (ALD(&flags[threadIdx.x * 16]) < target) {}
  }
  __builtin_amdgcn_sched_barrier(0);
  __syncthreads();
}

// ---------------- 16-step chunk kernel ----------------
// grid 128 = [li:1][ctile:6], block 256 = 4 waves; wave w -> rows w*16..w*16+15
__global__ void __launch_bounds__(256, 1) stepchunk(
    const float* __restrict__ cue,
    const short* __restrict__ w1t, const short* __restrict__ w2t,
    const short* __restrict__ w3t, const short* __restrict__ stab,
    const float* __restrict__ ca1bias, const float* __restrict__ ec5bias,
    const float* __restrict__ interb,
    unsigned* __restrict__ flags, unsigned* __restrict__ ec3u,
    unsigned* __restrict__ ca1u, float* __restrict__ ec5f, float* __restrict__ ec3f,
    float* __restrict__ ca1l, float* __restrict__ out, int t0, int base) {
  extern __shared__ short lds[];
  short* BT1 = lds;             // [16c][1024k] swizzled: idx = c*1024 + (k ^ ((c&7)<<3))
  short* BT2 = lds + 16 * 1024;
  short* BT3 = lds + 32 * 1024;

  const int b = blockIdx.x;
  const int li = b >> 6;
  const int c0 = (b & 63) << 4;
  const int tid = threadIdx.x;
  const int lane = tid & 63, wave = tid >> 6;
  const int fr = lane & 15, ks = lane >> 4;
  const int r0 = wave << 4;
  const int ccol = c0 + fr;

  // ---- stage weight slices into LDS once per chunk (vector loads, pre-swizzled dst)
  {
    int cp = tid & 15;              // local col
    int k0 = (tid >> 4) << 6;       // 64 k-elements per thread
    int xm = (cp & 7) << 3;
    const short* s1 = w1t + li * 1048576 + (c0 + cp) * 1024;
    const short* s2 = w2t + li * 1048576 + (c0 + cp) * 1024;
#pragma unroll
    for (int j = 0; j < 8; ++j) {
      int k = k0 + j * 8;
      *(bf16x8*)(BT1 + cp * 1024 + (k ^ xm)) = *(const bf16x8*)(s1 + k);
      *(bf16x8*)(BT2 + cp * 1024 + (k ^ xm)) = *(const bf16x8*)(s2 + k);
    }
    if (li == 1) {
      const short* s3 = w3t + (c0 + cp) * 1024;
#pragma unroll
      for (int j = 0; j < 8; ++j) {
        int k = k0 + j * 8;
        *(bf16x8*)(BT3 + cp * 1024 + (k ^ xm)) = *(const bf16x8*)(s3 + k);
      }
    }
  }
  __syncthreads();

  const int xsw = (fr & 7) << 3;
  const unsigned* A1u = ec3u + li * 32768 + (r0 + fr) * 512 + ks * 4;
  const unsigned* A2u = ca1u + li * 32768 + (r0 + fr) * 512 + ks * 4;
  const unsigned* A3u = ca1u + (r0 + fr) * 512 + ks * 4;          // layer-0 ca1
  const short* B1 = BT1 + fr * 1024;
  const short* B2 = BT2 + fr * 1024;
  const short* B3 = BT3 + fr * 1024;

  const float cb  = ca1bias[li * 1024 + ccol];
  const float e5b = ec5bias[li * 1024 + ccol];
  const float ib0 = interb[1024 + ccol];    // layer-1 inter_b (used when li==1)

  // block-exclusive fp32 state -> registers for the chunk
  float e5r[4], e3r[4];
#pragma unroll
  for (int r = 0; r < 4; ++r) {
    int sidx = li * 65536 + (r0 + ks * 4 + r) * 1024 + ccol;
    e5r[r] = ec5f[sidx];
    e3r[r] = ec3f[sidx];
  }

  unsigned tgt = (unsigned)base;
  bf16x8 ar[32];

  for (int tt = 0; tt < CHUNK; ++tt) {
    const int t = t0 + tt;

    float cueq[4];
    if (li == 0) {                        // prefetch cue for phase B (completes under A)
#pragma unroll
      for (int r = 0; r < 4; ++r)
        cueq[r] = cue[((r0 + ks * 4 + r) * Tn + t) * 1024 + ccol];
    }

    // ---------- phase A: ca1 = relu(S * (1 + 3*sig(ec3@W1)) - bias) ----------
    {
#pragma unroll
      for (int kk = 0; kk < 16; ++kk) {
        ar[kk]      = loadA(A1u + kk * 16);
        ar[16 + kk] = loadA(A1u + 256 + kk * 16);
      }
      __builtin_amdgcn_sched_barrier(0);   // bulk-issue all A loads before MFMAs
      f32x4 a0 = {0.f,0.f,0.f,0.f}, a1 = {0.f,0.f,0.f,0.f};
#pragma unroll
      for (int kk = 0; kk < 16; ++kk) {
        a0 = MFMA16(ar[kk],      *(const bf16x8*)(B1 + ((kk * 32 + ks * 8) ^ xsw)),       a0);
        a1 = MFMA16(ar[16 + kk], *(const bf16x8*)(B1 + ((512 + kk * 32 + ks * 8) ^ xsw)), a1);
      }
      f32x4 acc = a0 + a1;
      const float g = bf2f(stab[(li * Tn + t) * 1024 + ccol]);
#pragma unroll
      for (int r = 0; r < 4; ++r) {
        int grow = r0 + ks * 4 + r;
        float cv = fmaxf(g * (1.0f + 3.0f * sigm(acc[r])) - cb, 0.0f);
        unsigned my = f2bfu(cv);
        unsigned pr = (unsigned)__shfl_xor((int)my, 1);
        if ((fr & 1) == 0)
          AST(ca1u + li * 32768 + grow * 512 + ((c0 + fr) >> 1), my | (pr << 16));
        if (grow == 0) out[OUT_CA1 + (li * Tn + t) * 1024 + ccol] = cv;
        if (t == Tn - 1 && li == 1) ca1l[grow * 1024 + ccol] = cv;
      }
    }
    gridbar(flags, ++tgt);

    // ---------- phase B: ec5/ec3 update ----------
    {
#pragma unroll
      for (int kk = 0; kk < 16; ++kk) {
        ar[kk]      = loadA(A2u + kk * 16);
        ar[16 + kk] = loadA(A2u + 256 + kk * 16);
      }
      __builtin_amdgcn_sched_barrier(0);
      f32x4 p0 = {0.f,0.f,0.f,0.f}, p1 = {0.f,0.f,0.f,0.f};
#pragma unroll
      for (int kk = 0; kk < 16; ++kk) {
        p0 = MFMA16(ar[kk],      *(const bf16x8*)(B2 + ((kk * 32 + ks * 8) ^ xsw)),       p0);
        p1 = MFMA16(ar[16 + kk], *(const bf16x8*)(B2 + ((512 + kk * 32 + ks * 8) ^ xsw)), p1);
      }
      f32x4 g2 = p0 + p1;

      f32x4 xin;
      if (li == 1) {
#pragma unroll
        for (int kk = 0; kk < 16; ++kk) {
          ar[kk]      = loadA(A3u + kk * 16);
          ar[16 + kk] = loadA(A3u + 256 + kk * 16);
        }
        __builtin_amdgcn_sched_barrier(0);
        f32x4 q0 = {0.f,0.f,0.f,0.f}, q1 = {0.f,0.f,0.f,0.f};
#pragma unroll
        for (int kk = 0; kk < 16; ++kk) {
          q0 = MFMA16(ar[kk],      *(const bf16x8*)(B3 + ((kk * 32 + ks * 8) ^ xsw)),       q0);
          q1 = MFMA16(ar[16 + kk], *(const bf16x8*)(B3 + ((512 + kk * 32 + ks * 8) ^ xsw)), q1);
        }
        f32x4 q = q0 + q1;
#pragma unroll
        for (int r = 0; r < 4; ++r) xin[r] = q[r] + ib0;
      } else {
#pragma unroll
        for (int r = 0; r < 4; ++r) xin[r] = cueq[r];
      }

#pragma unroll
      for (int r = 0; r < 4; ++r) {
        int grow = r0 + ks * 4 + r;
        float raw = e5r[r] + g2[r] + e5b;            // 10*TS == 1.0f exactly
        float e5 = 0.69f + 0.3f * sigm(4.0f * (raw - 0.3f));
        e5r[r] = e5;
        float e3 = e5 * e3r[r] + 0.6f * xin[r];
        e3r[r] = e3;
        unsigned my = f2bfu(e3);
        unsigned pr = (unsigned)__shfl_xor((int)my, 1);
        if ((fr & 1) == 0)
          AST(ec3u + li * 32768 + grow * 512 + ((c0 + fr) >> 1), my | (pr << 16));
        if (grow == 0) {
          out[OUT_E5 + (li * Tn + t) * 1024 + ccol] = e5;
          out[OUT_E3 + (li * Tn + t) * 1024 + ccol] = e3;
        }
      }
    }
    gridbar(flags, ++tgt);
  }

  // spill fp32 state for next chunk (dispatch boundary provides coherence)
#pragma unroll
  for (int r = 0; r < 4; ++r) {
    int sidx = li * 65536 + (r0 + ks * 4 + r) * 1024 + ccol;
    ec5f[sidx] = e5r[r];
    ec3f[sidx] = e3r[r];
  }
}

__global__ void act_cell(const float* __restrict__ ca1l, const float* __restrict__ wca1act,
                         const float* __restrict__ actbias, float* __restrict__ out) {
  int tid = threadIdx.x;
  if (tid < 128) {
    int b = tid >> 1, a = tid & 1;
    float s = 0.0f;
    for (int k = 0; k < 1024; ++k) s += ca1l[b * 1024 + k] * wca1act[k * 2 + a];
    out[b * 2 + a] = s + actbias[a];
  }
}

extern "C" void kernel_launch(void* const* d_in, const int* in_sizes, int n_in,
                              void* d_out, int out_size, void* d_ws, size_t ws_size,
                              hipStream_t stream) {
  (void)in_sizes; (void)n_in; (void)out_size; (void)ws_size;
  const float* cue      = (const float*)d_in[0];
  const float* ec3_last = (const float*)d_in[1];
  const float* ec5_last = (const float*)d_in[2];
  const float* wca3ca1  = (const float*)d_in[4];
  const float* wec3ca1  = (const float*)d_in[5];
  const float* wca1ec5  = (const float*)d_in[6];
  const float* ca1bias  = (const float*)d_in[7];
  const float* ec5bias  = (const float*)d_in[8];
  const float* inter_w  = (const float*)d_in[9];
  const float* inter_b  = (const float*)d_in[10];
  const float* wca1act  = (const float*)d_in[11];
  const float* actbias  = (const float*)d_in[12];
  float* out = (float*)d_out;

  char* ws = (char*)d_ws;
  unsigned* flags = (unsigned*)(ws + WS_FLAGS);
  unsigned* ec3u  = (unsigned*)(ws + WS_EC3U);
  unsigned* ca1u  = (unsigned*)(ws + WS_CA1U);
  float* ec5f = (float*)(ws + WS_EC5F);
  float* ec3f = (float*)(ws + WS_EC3F);
  float* ca1l = (float*)(ws + WS_CA1L);
  short* stab = (short*)(ws + WS_S);
  short* w1t  = (short*)(ws + WS_W1T);
  short* w2t  = (short*)(ws + WS_W2T);
  short* w3t  = (short*)(ws + WS_W3T);

  prep_state<<<dim3(512), dim3(256), 0, stream>>>(ec3_last, ec5_last, flags, ec3u, ec5f, ec3f);
  prep_wt<<<dim3(1024), dim3(256), 0, stream>>>(wec3ca1, wca1ec5, w1t, w2t);
  prep_w3<<<dim3(4096), dim3(256), 0, stream>>>(inter_w, w3t);
  prep_ca3<<<dim3(1024), dim3(256), 0, stream>>>(wca3ca1, stab);

  hipFuncSetAttribute((const void*)stepchunk,
                      hipFuncAttributeMaxDynamicSharedMemorySize, 98304);

  for (int c = 0; c < Tn / CHUNK; ++c) {
    stepchunk<<<dim3(128), dim3(256), 98304, stream>>>(
        cue, w1t, w2t, w3t, stab, ca1bias, ec5bias, inter_b,
        flags, ec3u, ca1u, ec5f, ec3f, ca1l, out, c * CHUNK, c * 2 * CHUNK);
  }

  act_cell<<<dim3(1), dim3(128), 0, stream>>>(ca1l, wca1act, actbias, out);
}

// Round 7
// 11220.323 us; speedup vs baseline: 2.4493x; 2.1234x over previous
//
#include <hip/hip_runtime.h>

#define Lnum 2
#define BSn  64
#define Tn   512
#define ECn  1024
#define CA1n 1024
#define CHUNK 16

typedef short bf16x8 __attribute__((ext_vector_type(8)));
typedef float f32x4  __attribute__((ext_vector_type(4)));

#define MFMA16(a,b,c) __builtin_amdgcn_mfma_f32_16x16x32_bf16((a),(b),(c),0,0,0)

// d_out layout: [actCell 64*2][ec3his 2*512*1024][ec5his ...][ca1his ...]
#define OUT_E3  128
#define OUT_E5  (128 + Lnum*Tn*ECn)
#define OUT_CA1 (128 + 2*Lnum*Tn*ECn)

// ws layout (bytes)
#define WS_FLAGS 0                      // 128 flags * 64B
#define WS_EC3S  8192                   // bf16 [16 slot][2 L][64][1024] = 4MB
#define WS_CA1S  4202496                // bf16 [16 slot][2 L][64][1024] = 4MB
#define WS_EC5F  8396800                // f32 [2][64][1024]
#define WS_EC3F  8921088                // f32 [2][64][1024]
#define WS_CA1L  9445376                // f32 [64][1024]
#define WS_S     9707520                // bf16 [2][512][1024]
#define WS_W1T   11804672               // bf16 [2][1024c][1024k]
#define WS_W2T   15998976               // bf16 [2][1024e][1024k]
#define WS_W3T   20193280               // bf16 [1024e][1024k]  (ends ~22.3MB)

#define AST(p, v) __hip_atomic_store((p), (v), __ATOMIC_RELAXED, __HIP_MEMORY_SCOPE_AGENT)
#define ALD(p)    __hip_atomic_load((p), __ATOMIC_RELAXED, __HIP_MEMORY_SCOPE_AGENT)

__device__ __forceinline__ float sigm(float x) { return 1.0f / (1.0f + __expf(-x)); }

__device__ __forceinline__ unsigned f2bfu(float f) {
  unsigned u = __float_as_uint(f);
  u += 0x7fffu + ((u >> 16) & 1u);   // RNE
  return u >> 16;
}
__device__ __forceinline__ short f2bf(float f) { return (short)f2bfu(f); }
__device__ __forceinline__ float bf2f(short s) {
  return __uint_as_float(((unsigned)(unsigned short)s) << 16);
}

// ---------------- prep kernels (R4/R5/R6-proven) ----------------

__global__ void prep_state(const float* __restrict__ ec3_last,
                           const float* __restrict__ ec5_last,
                           unsigned* __restrict__ flags, unsigned* __restrict__ ec3su,
                           float* __restrict__ ec5f, float* __restrict__ ec3f) {
  int i = blockIdx.x * blockDim.x + threadIdx.x;   // 512*256 = 131072
  if (i < 2048) flags[i] = 0u;
  float v3 = ec3_last[i];
  ec3f[i] = v3;
  ec5f[i] = ec5_last[i];
  if (i < Lnum * BSn * 512) {      // pack initial ec3 into slot 15
    float lo = ec3_last[2 * i], hi = ec3_last[2 * i + 1];
    ec3su[15 * 65536 + i] = f2bfu(lo) | (f2bfu(hi) << 16);
  }
}

// 64x64 LDS tile transpose fp32[k][c] -> bf16[c][k], for W1 (m=0) and W2 (m=1)
__global__ void prep_wt(const float* __restrict__ w1, const float* __restrict__ w2,
                        short* __restrict__ w1t, short* __restrict__ w2t) {
  __shared__ float tile[64][65];
  const int b = blockIdx.x;               // 1024 = 2 mats * 2 layers * 16*16 tiles
  const int m  = b >> 9;
  const int li = (b >> 8) & 1;
  const int kt = (b >> 4) & 15;
  const int ct = b & 15;
  const float* src = (m == 0 ? w1 : w2) + li * (1024 * 1024);
  short* dst = (m == 0 ? w1t : w2t) + li * (1024 * 1024);
#pragma unroll
  for (int i = 0; i < 16; ++i) {
    int idx = threadIdx.x + i * 256;
    int r = idx >> 6, c = idx & 63;
    tile[r][c] = src[(kt * 64 + r) * 1024 + ct * 64 + c];
  }
  __syncthreads();
#pragma unroll
  for (int i = 0; i < 16; ++i) {
    int idx = threadIdx.x + i * 256;
    int c = idx >> 6, r = idx & 63;
    dst[(ct * 64 + c) * 1024 + kt * 64 + r] = f2bf(tile[r][c]);
  }
}

__global__ void prep_w3(const float* __restrict__ inter_w, short* __restrict__ w3t) {
  int i = blockIdx.x * blockDim.x + threadIdx.x;   // 4096*256 = 1048576
  w3t[i] = f2bf(inter_w[i]);                        // layer 0, already [e][k]
}

__global__ void prep_ca3(const float* __restrict__ wca3ca1, short* __restrict__ S) {
  const int t = blockIdx.x >> 1, li = blockIdx.x & 1;
  __shared__ float gauss[192];
  const float stepc = 512.0f / 1023.0f;
  const float tf = (float)t;
  int kmin = (int)floorf((tf - 40.0f) / stepc) - 1; if (kmin < 0) kmin = 0;
  int kmax = (int)ceilf((tf + 40.0f) / stepc) + 1;  if (kmax > 1023) kmax = 1023;
  int nw = kmax - kmin + 1;
  for (int j = threadIdx.x; j < nw; j += 256) {
    float d = (float)(kmin + j) * stepc - tf;
    gauss[j] = __expf(-d * d * 0.02f);
  }
  __syncthreads();
  const float* W = wca3ca1 + li * (1024 * 1024);
  for (int c = threadIdx.x; c < 1024; c += 256) {
    float s = 0.0f;
    for (int j = 0; j < nw; ++j) s += gauss[j] * W[(kmin + j) * 1024 + c];
    S[(li * Tn + t) * 1024 + c] = f2bf(sigm(10.0f * (s - 0.5f)));
  }
}

// ---- flag-array grid barrier (128 blocks; mutable data is slot-rotated) ----
__device__ __forceinline__ void gridbar(unsigned* flags, unsigned target) {
  asm volatile("s_waitcnt vmcnt(0)" ::: "memory");  // own sc1 stores acked at IF$
  __syncthreads();                                  // => all waves' stores acked
  if (threadIdx.x == 0) AST(&flags[blockIdx.x * 16], target);
  if (threadIdx.x < 128) {
    while (ALD(&flags[threadIdx.x * 16]) < target) {}
  }
  __builtin_amdgcn_sched_barrier(0);
  __syncthreads();
}

// ---------------- 16-step chunk kernel ----------------
// grid 128 = [li:1][ctile:6], block 256 = 4 waves; wave w -> rows w*16..w*16+15
// Activation exchange: write slot[tt] via sc1 packed-u32 stores (write-through to
// IF$); read via PLAIN CACHED bf16x8 loads. A slot's lines are only demand-fetched
// after their write (barrier-ordered), so no stale copy can exist within a
// dispatch; across dispatches the CP acquire-invalidate resets caches.
__global__ void __launch_bounds__(256, 1) stepchunk(
    const float* __restrict__ cue,
    const short* __restrict__ w1t, const short* __restrict__ w2t,
    const short* __restrict__ w3t, const short* __restrict__ stab,
    const float* __restrict__ ca1bias, const float* __restrict__ ec5bias,
    const float* __restrict__ interb,
    unsigned* __restrict__ flags, short* __restrict__ ec3s,
    short* __restrict__ ca1s, float* __restrict__ ec5f, float* __restrict__ ec3f,
    float* __restrict__ ca1l, float* __restrict__ out, int t0, int base) {
  extern __shared__ short lds[];
  short* BT1 = lds;             // [16c][1024k] swizzled: idx = c*1024 + (k ^ ((c&7)<<3))
  short* BT2 = lds + 16 * 1024;
  short* BT3 = lds + 32 * 1024;

  unsigned* ec3su = (unsigned*)ec3s;
  unsigned* ca1su = (unsigned*)ca1s;

  const int b = blockIdx.x;
  const int li = b >> 6;
  const int c0 = (b & 63) << 4;
  const int tid = threadIdx.x;
  const int lane = tid & 63, wave = tid >> 6;
  const int fr = lane & 15, ks = lane >> 4;
  const int r0 = wave << 4;
  const int ccol = c0 + fr;

  // ---- stage weight slices into LDS once per chunk (vector loads, swizzled dst)
  {
    int cp = tid & 15;
    int k0 = (tid >> 4) << 6;
    int xm = (cp & 7) << 3;
    const short* s1 = w1t + li * 1048576 + (c0 + cp) * 1024;
    const short* s2 = w2t + li * 1048576 + (c0 + cp) * 1024;
#pragma unroll
    for (int j = 0; j < 8; ++j) {
      int k = k0 + j * 8;
      *(bf16x8*)(BT1 + cp * 1024 + (k ^ xm)) = *(const bf16x8*)(s1 + k);
      *(bf16x8*)(BT2 + cp * 1024 + (k ^ xm)) = *(const bf16x8*)(s2 + k);
    }
    if (li == 1) {
      const short* s3 = w3t + (c0 + cp) * 1024;
#pragma unroll
      for (int j = 0; j < 8; ++j) {
        int k = k0 + j * 8;
        *(bf16x8*)(BT3 + cp * 1024 + (k ^ xm)) = *(const bf16x8*)(s3 + k);
      }
    }
  }
  __syncthreads();

  const int xsw = (fr & 7) << 3;
  const short* B1 = BT1 + fr * 1024;
  const short* B2 = BT2 + fr * 1024;
  const short* B3 = BT3 + fr * 1024;

  const float cb  = ca1bias[li * 1024 + ccol];
  const float e5b = ec5bias[li * 1024 + ccol];
  const float ib0 = interb[1024 + ccol];    // layer-1 inter_b (used when li==1)

  // block-exclusive fp32 state -> registers for the chunk
  float e5r[4], e3r[4];
#pragma unroll
  for (int r = 0; r < 4; ++r) {
    int sidx = li * 65536 + (r0 + ks * 4 + r) * 1024 + ccol;
    e5r[r] = ec5f[sidx];
    e3r[r] = ec3f[sidx];
  }

  unsigned tgt = (unsigned)base;

  for (int tt = 0; tt < CHUNK; ++tt) {
    const int t = t0 + tt;
    const int rd = (tt + 15) & 15;   // ec3 slot written last step (15 = initial/prev chunk)

    float cueq[4];
    if (li == 0) {                        // prefetch cue for phase B (completes under A)
#pragma unroll
      for (int r = 0; r < 4; ++r)
        cueq[r] = cue[((r0 + ks * 4 + r) * Tn + t) * 1024 + ccol];
    }

    // ---------- phase A: ca1 = relu(S * (1 + 3*sig(ec3@W1)) - bias) ----------
    {
      const short* A1 = ec3s + ((rd * 2 + li) * 64 + (r0 + fr)) * 1024 + ks * 8;
      f32x4 a0 = {0.f,0.f,0.f,0.f}, a1 = {0.f,0.f,0.f,0.f};
#pragma unroll
      for (int kk = 0; kk < 16; ++kk) {
        a0 = MFMA16(*(const bf16x8*)(A1 + kk * 32),
                    *(const bf16x8*)(B1 + ((kk * 32 + ks * 8) ^ xsw)), a0);
        a1 = MFMA16(*(const bf16x8*)(A1 + 512 + kk * 32),
                    *(const bf16x8*)(B1 + ((512 + kk * 32 + ks * 8) ^ xsw)), a1);
      }
      f32x4 acc = a0 + a1;
      const float g = bf2f(stab[(li * Tn + t) * 1024 + ccol]);
#pragma unroll
      for (int r = 0; r < 4; ++r) {
        int grow = r0 + ks * 4 + r;
        float cv = fmaxf(g * (1.0f + 3.0f * sigm(acc[r])) - cb, 0.0f);
        unsigned my = f2bfu(cv);
        unsigned pr = (unsigned)__shfl_xor((int)my, 1);
        if ((fr & 1) == 0)
          AST(ca1su + ((tt * 2 + li) * 64 + grow) * 512 + ((c0 + fr) >> 1), my | (pr << 16));
        if (grow == 0) out[OUT_CA1 + (li * Tn + t) * 1024 + ccol] = cv;
        if (t == Tn - 1 && li == 1) ca1l[grow * 1024 + ccol] = cv;
      }
    }
    gridbar(flags, ++tgt);

    // ---------- phase B: ec5/ec3 update ----------
    {
      const short* A2 = ca1s + ((tt * 2 + li) * 64 + (r0 + fr)) * 1024 + ks * 8;
      f32x4 p0 = {0.f,0.f,0.f,0.f}, p1 = {0.f,0.f,0.f,0.f};
#pragma unroll
      for (int kk = 0; kk < 16; ++kk) {
        p0 = MFMA16(*(const bf16x8*)(A2 + kk * 32),
                    *(const bf16x8*)(B2 + ((kk * 32 + ks * 8) ^ xsw)), p0);
        p1 = MFMA16(*(const bf16x8*)(A2 + 512 + kk * 32),
                    *(const bf16x8*)(B2 + ((512 + kk * 32 + ks * 8) ^ xsw)), p1);
      }
      f32x4 g2 = p0 + p1;

      f32x4 xin;
      if (li == 1) {
        const short* A3 = ca1s + ((tt * 2) * 64 + (r0 + fr)) * 1024 + ks * 8;
        f32x4 q0 = {0.f,0.f,0.f,0.f}, q1 = {0.f,0.f,0.f,0.f};
#pragma unroll
        for (int kk = 0; kk < 16; ++kk) {
          q0 = MFMA16(*(const bf16x8*)(A3 + kk * 32),
                      *(const bf16x8*)(B3 + ((kk * 32 + ks * 8) ^ xsw)), q0);
          q1 = MFMA16(*(const bf16x8*)(A3 + 512 + kk * 32),
                      *(const bf16x8*)(B3 + ((512 + kk * 32 + ks * 8) ^ xsw)), q1);
        }
        f32x4 q = q0 + q1;
#pragma unroll
        for (int r = 0; r < 4; ++r) xin[r] = q[r] + ib0;
      } else {
#pragma unroll
        for (int r = 0; r < 4; ++r) xin[r] = cueq[r];
      }

#pragma unroll
      for (int r = 0; r < 4; ++r) {
        int grow = r0 + ks * 4 + r;
        float raw = e5r[r] + g2[r] + e5b;            // 10*TS == 1.0f exactly
        float e5 = 0.69f + 0.3f * sigm(4.0f * (raw - 0.3f));
        e5r[r] = e5;
        float e3 = e5 * e3r[r] + 0.6f * xin[r];
        e3r[r] = e3;
        unsigned my = f2bfu(e3);
        unsigned pr = (unsigned)__shfl_xor((int)my, 1);
        if ((fr & 1) == 0)
          AST(ec3su + ((tt * 2 + li) * 64 + grow) * 512 + ((c0 + fr) >> 1), my | (pr << 16));
        if (grow == 0) {
          out[OUT_E5 + (li * Tn + t) * 1024 + ccol] = e5;
          out[OUT_E3 + (li * Tn + t) * 1024 + ccol] = e3;
        }
      }
    }
    gridbar(flags, ++tgt);
  }

  // spill fp32 state for next chunk (dispatch boundary provides coherence)
#pragma unroll
  for (int r = 0; r < 4; ++r) {
    int sidx = li * 65536 + (r0 + ks * 4 + r) * 1024 + ccol;
    ec5f[sidx] = e5r[r];
    ec3f[sidx] = e3r[r];
  }
}

__global__ void act_cell(const float* __restrict__ ca1l, const float* __restrict__ wca1act,
                         const float* __restrict__ actbias, float* __restrict__ out) {
  int tid = threadIdx.x;
  if (tid < 128) {
    int b = tid >> 1, a = tid & 1;
    float s = 0.0f;
    for (int k = 0; k < 1024; ++k) s += ca1l[b * 1024 + k] * wca1act[k * 2 + a];
    out[b * 2 + a] = s + actbias[a];
  }
}

extern "C" void kernel_launch(void* const* d_in, const int* in_sizes, int n_in,
                              void* d_out, int out_size, void* d_ws, size_t ws_size,
                              hipStream_t stream) {
  (void)in_sizes; (void)n_in; (void)out_size; (void)ws_size;
  const float* cue      = (const float*)d_in[0];
  const float* ec3_last = (const float*)d_in[1];
  const float* ec5_last = (const float*)d_in[2];
  const float* wca3ca1  = (const float*)d_in[4];
  const float* wec3ca1  = (const float*)d_in[5];
  const float* wca1ec5  = (const float*)d_in[6];
  const float* ca1bias  = (const float*)d_in[7];
  const float* ec5bias  = (const float*)d_in[8];
  const float* inter_w  = (const float*)d_in[9];
  const float* inter_b  = (const float*)d_in[10];
  const float* wca1act  = (const float*)d_in[11];
  const float* actbias  = (const float*)d_in[12];
  float* out = (float*)d_out;

  char* ws = (char*)d_ws;
  unsigned* flags = (unsigned*)(ws + WS_FLAGS);
  short* ec3s = (short*)(ws + WS_EC3S);
  short* ca1s = (short*)(ws + WS_CA1S);
  float* ec5f = (float*)(ws + WS_EC5F);
  float* ec3f = (float*)(ws + WS_EC3F);
  float* ca1l = (float*)(ws + WS_CA1L);
  short* stab = (short*)(ws + WS_S);
  short* w1t  = (short*)(ws + WS_W1T);
  short* w2t  = (short*)(ws + WS_W2T);
  short* w3t  = (short*)(ws + WS_W3T);

  prep_state<<<dim3(512), dim3(256), 0, stream>>>(ec3_last, ec5_last, flags,
                                                  (unsigned*)ec3s, ec5f, ec3f);
  prep_wt<<<dim3(1024), dim3(256), 0, stream>>>(wec3ca1, wca1ec5, w1t, w2t);
  prep_w3<<<dim3(4096), dim3(256), 0, stream>>>(inter_w, w3t);
  prep_ca3<<<dim3(1024), dim3(256), 0, stream>>>(wca3ca1, stab);

  hipFuncSetAttribute((const void*)stepchunk,
                      hipFuncAttributeMaxDynamicSharedMemorySize, 98304);

  for (int c = 0; c < Tn / CHUNK; ++c) {
    stepchunk<<<dim3(128), dim3(256), 98304, stream>>>(
        cue, w1t, w2t, w3t, stab, ca1bias, ec5bias, inter_b,
        flags, ec3s, ca1s, ec5f, ec3f, ca1l, out, c * CHUNK, c * 2 * CHUNK);
  }

  act_cell<<<dim3(1), dim3(128), 0, stream>>>(ca1l, wca1act, actbias, out);
}

// Round 8
// 10776.828 us; speedup vs baseline: 2.5501x; 1.0412x over previous
//
#include <hip/hip_runtime.h>

#define Lnum 2
#define BSn  64
#define Tn   512
#define ECn  1024
#define CA1n 1024
#define CHUNK 16

typedef short bf16x8 __attribute__((ext_vector_type(8)));
typedef float f32x4  __attribute__((ext_vector_type(4)));

#define MFMA16(a,b,c) __builtin_amdgcn_mfma_f32_16x16x32_bf16((a),(b),(c),0,0,0)

// d_out layout: [actCell 64*2][ec3his 2*512*1024][ec5his ...][ca1his ...]
#define OUT_E3  128
#define OUT_E5  (128 + Lnum*Tn*ECn)
#define OUT_CA1 (128 + 2*Lnum*Tn*ECn)

// ws layout (bytes)
#define WS_FLAGS 0                      // counter @ word 0
#define WS_EC3S  8192                   // bf16 [16 slot][2 L][64][1024] = 4MB
#define WS_CA1S  4202496                // bf16 [16 slot][2 L][64][1024] = 4MB
#define WS_EC5F  8396800                // f32 [2][64][1024]
#define WS_EC3F  8921088                // f32 [2][64][1024]
#define WS_CA1L  9445376                // f32 [64][1024]
#define WS_S     9707520                // bf16 [2][512][1024]
#define WS_W1T   11804672               // bf16 [2][1024c][1024k]
#define WS_W2T   15998976               // bf16 [2][1024e][1024k]
#define WS_W3T   20193280               // bf16 [1024e][1024k]  (ends ~22.3MB)

#define AST(p, v) __hip_atomic_store((p), (v), __ATOMIC_RELAXED, __HIP_MEMORY_SCOPE_AGENT)
#define ALD(p)    __hip_atomic_load((p), __ATOMIC_RELAXED, __HIP_MEMORY_SCOPE_AGENT)

__device__ __forceinline__ float sigm(float x) { return 1.0f / (1.0f + __expf(-x)); }

__device__ __forceinline__ unsigned f2bfu(float f) {
  unsigned u = __float_as_uint(f);
  u += 0x7fffu + ((u >> 16) & 1u);   // RNE
  return u >> 16;
}
__device__ __forceinline__ short f2bf(float f) { return (short)f2bfu(f); }
__device__ __forceinline__ float bf2f(short s) {
  return __uint_as_float(((unsigned)(unsigned short)s) << 16);
}

// ---------------- prep kernels (R4-R7 proven) ----------------

__global__ void prep_state(const float* __restrict__ ec3_last,
                           const float* __restrict__ ec5_last,
                           unsigned* __restrict__ flags, unsigned* __restrict__ ec3su,
                           float* __restrict__ ec5f, float* __restrict__ ec3f) {
  int i = blockIdx.x * blockDim.x + threadIdx.x;   // 512*256 = 131072
  if (i < 2048) flags[i] = 0u;
  float v3 = ec3_last[i];
  ec3f[i] = v3;
  ec5f[i] = ec5_last[i];
  if (i < Lnum * BSn * 512) {      // pack initial ec3 into slot 15
    float lo = ec3_last[2 * i], hi = ec3_last[2 * i + 1];
    ec3su[15 * 65536 + i] = f2bfu(lo) | (f2bfu(hi) << 16);
  }
}

// 64x64 LDS tile transpose fp32[k][c] -> bf16[c][k], for W1 (m=0) and W2 (m=1)
__global__ void prep_wt(const float* __restrict__ w1, const float* __restrict__ w2,
                        short* __restrict__ w1t, short* __restrict__ w2t) {
  __shared__ float tile[64][65];
  const int b = blockIdx.x;               // 1024 = 2 mats * 2 layers * 16*16 tiles
  const int m  = b >> 9;
  const int li = (b >> 8) & 1;
  const int kt = (b >> 4) & 15;
  const int ct = b & 15;
  const float* src = (m == 0 ? w1 : w2) + li * (1024 * 1024);
  short* dst = (m == 0 ? w1t : w2t) + li * (1024 * 1024);
#pragma unroll
  for (int i = 0; i < 16; ++i) {
    int idx = threadIdx.x + i * 256;
    int r = idx >> 6, c = idx & 63;
    tile[r][c] = src[(kt * 64 + r) * 1024 + ct * 64 + c];
  }
  __syncthreads();
#pragma unroll
  for (int i = 0; i < 16; ++i) {
    int idx = threadIdx.x + i * 256;
    int c = idx >> 6, r = idx & 63;
    dst[(ct * 64 + c) * 1024 + kt * 64 + r] = f2bf(tile[r][c]);
  }
}

__global__ void prep_w3(const float* __restrict__ inter_w, short* __restrict__ w3t) {
  int i = blockIdx.x * blockDim.x + threadIdx.x;   // 4096*256 = 1048576
  w3t[i] = f2bf(inter_w[i]);                        // layer 0, already [e][k]
}

__global__ void prep_ca3(const float* __restrict__ wca3ca1, short* __restrict__ S) {
  const int t = blockIdx.x >> 1, li = blockIdx.x & 1;
  __shared__ float gauss[192];
  const float stepc = 512.0f / 1023.0f;
  const float tf = (float)t;
  int kmin = (int)floorf((tf - 40.0f) / stepc) - 1; if (kmin < 0) kmin = 0;
  int kmax = (int)ceilf((tf + 40.0f) / stepc) + 1;  if (kmax > 1023) kmax = 1023;
  int nw = kmax - kmin + 1;
  for (int j = threadIdx.x; j < nw; j += 256) {
    float d = (float)(kmin + j) * stepc - tf;
    gauss[j] = __expf(-d * d * 0.02f);
  }
  __syncthreads();
  const float* W = wca3ca1 + li * (1024 * 1024);
  for (int c = threadIdx.x; c < 1024; c += 256) {
    float s = 0.0f;
    for (int j = 0; j < nw; ++j) s += gauss[j] * W[(kmin + j) * 1024 + c];
    S[(li * Tn + t) * 1024 + c] = f2bf(sigm(10.0f * (s - 0.5f)));
  }
}

// ---- counter grid barrier: 1 atomicAdd + 1-word poll per block ----
__device__ __forceinline__ void gridbar(unsigned* cnt, unsigned target) {
  asm volatile("s_waitcnt vmcnt(0)" ::: "memory");  // own sc1 stores acked at IF$
  __syncthreads();                                  // => all waves' stores acked
  if (threadIdx.x == 0) {
    __hip_atomic_fetch_add(cnt, 1u, __ATOMIC_RELAXED, __HIP_MEMORY_SCOPE_AGENT);
    while (ALD(cnt) < target) {}
  }
  __builtin_amdgcn_sched_barrier(0);
  __syncthreads();
}

// ---------------- 16-step chunk kernel ----------------
// grid 128 = [li:1][ctile:6], block 256 = 4 waves; wave w -> rows w*16..w*16+15
// Activation exchange: write slot[tt] via sc1 packed-u32 stores; read via PLAIN
// CACHED bulk vector loads (slot lines only demand-fetched after their write;
// dispatch-boundary acquire resets caches between chunks). R7-proven.
__global__ void __launch_bounds__(256, 1) stepchunk(
    const float* __restrict__ cue,
    const short* __restrict__ w1t, const short* __restrict__ w2t,
    const short* __restrict__ w3t, const short* __restrict__ stab,
    const float* __restrict__ ca1bias, const float* __restrict__ ec5bias,
    const float* __restrict__ interb,
    unsigned* __restrict__ flags, short* __restrict__ ec3s,
    short* __restrict__ ca1s, float* __restrict__ ec5f, float* __restrict__ ec3f,
    float* __restrict__ ca1l, float* __restrict__ out, int t0, int barbase) {
  extern __shared__ short lds[];
  short* BT1 = lds;             // [16c][1024k] swizzled: idx = c*1024 + (k ^ ((c&7)<<3))
  short* BT2 = lds + 16 * 1024;
  short* BT3 = lds + 32 * 1024;

  unsigned* ec3su = (unsigned*)ec3s;
  unsigned* ca1su = (unsigned*)ca1s;

  const int b = blockIdx.x;
  const int li = b >> 6;
  const int c0 = (b & 63) << 4;
  const int tid = threadIdx.x;
  const int lane = tid & 63, wave = tid >> 6;
  const int fr = lane & 15, ks = lane >> 4;
  const int r0 = wave << 4;
  const int ccol = c0 + fr;

  // ---- stage weight slices into LDS once per chunk
  {
    int cp = tid & 15;
    int k0 = (tid >> 4) << 6;
    int xm = (cp & 7) << 3;
    const short* s1 = w1t + li * 1048576 + (c0 + cp) * 1024;
    const short* s2 = w2t + li * 1048576 + (c0 + cp) * 1024;
#pragma unroll
    for (int j = 0; j < 8; ++j) {
      int k = k0 + j * 8;
      *(bf16x8*)(BT1 + cp * 1024 + (k ^ xm)) = *(const bf16x8*)(s1 + k);
      *(bf16x8*)(BT2 + cp * 1024 + (k ^ xm)) = *(const bf16x8*)(s2 + k);
    }
    if (li == 1) {
      const short* s3 = w3t + (c0 + cp) * 1024;
#pragma unroll
      for (int j = 0; j < 8; ++j) {
        int k = k0 + j * 8;
        *(bf16x8*)(BT3 + cp * 1024 + (k ^ xm)) = *(const bf16x8*)(s3 + k);
      }
    }
  }
  __syncthreads();

  const int xsw = (fr & 7) << 3;
  const short* B1 = BT1 + fr * 1024;
  const short* B2 = BT2 + fr * 1024;
  const short* B3 = BT3 + fr * 1024;

  const float cb  = ca1bias[li * 1024 + ccol];
  const float e5b = ec5bias[li * 1024 + ccol];
  const float ib0 = interb[1024 + ccol];    // layer-1 inter_b (used when li==1)

  // block-exclusive fp32 state -> registers for the chunk
  float e5r[4], e3r[4];
#pragma unroll
  for (int r = 0; r < 4; ++r) {
    int sidx = li * 65536 + (r0 + ks * 4 + r) * 1024 + ccol;
    e5r[r] = ec5f[sidx];
    e3r[r] = ec3f[sidx];
  }

  unsigned nb = (unsigned)barbase;
  bf16x8 ar[32], ar3[32];

  for (int tt = 0; tt < CHUNK; ++tt) {
    const int t = t0 + tt;
    const int rd = (tt + 15) & 15;   // ec3 slot written last step (15 = initial/prev)

    float cueq[4];
    if (li == 0) {                        // prefetch cue (completes under phase A)
#pragma unroll
      for (int r = 0; r < 4; ++r)
        cueq[r] = cue[((r0 + ks * 4 + r) * Tn + t) * 1024 + ccol];
    }

    // ---------- phase A: ca1 = relu(S * (1 + 3*sig(ec3@W1)) - bias) ----------
    {
      const short* A1 = ec3s + ((rd * 2 + li) * 64 + (r0 + fr)) * 1024 + ks * 8;
#pragma unroll
      for (int kk = 0; kk < 16; ++kk) {
        ar[kk]      = *(const bf16x8*)(A1 + kk * 32);
        ar[16 + kk] = *(const bf16x8*)(A1 + 512 + kk * 32);
      }
      __builtin_amdgcn_sched_barrier(0);   // bulk-issue all 32 loads first (MLP)
      f32x4 a0 = {0.f,0.f,0.f,0.f}, a1 = {0.f,0.f,0.f,0.f};
#pragma unroll
      for (int kk = 0; kk < 16; ++kk) {
        a0 = MFMA16(ar[kk],      *(const bf16x8*)(B1 + ((kk * 32 + ks * 8) ^ xsw)),       a0);
        a1 = MFMA16(ar[16 + kk], *(const bf16x8*)(B1 + ((512 + kk * 32 + ks * 8) ^ xsw)), a1);
      }
      f32x4 acc = a0 + a1;
      const float g = bf2f(stab[(li * Tn + t) * 1024 + ccol]);
#pragma unroll
      for (int r = 0; r < 4; ++r) {
        int grow = r0 + ks * 4 + r;
        float cv = fmaxf(g * (1.0f + 3.0f * sigm(acc[r])) - cb, 0.0f);
        unsigned my = f2bfu(cv);
        unsigned pr = (unsigned)__shfl_xor((int)my, 1);
        if ((fr & 1) == 0)
          AST(ca1su + ((tt * 2 + li) * 64 + grow) * 512 + ((c0 + fr) >> 1), my | (pr << 16));
        if (grow == 0) out[OUT_CA1 + (li * Tn + t) * 1024 + ccol] = cv;
        if (t == Tn - 1 && li == 1) ca1l[grow * 1024 + ccol] = cv;
      }
    }
    gridbar(flags, (++nb) * 128u);

    // ---------- phase B: ec5/ec3 update ----------
    {
      const short* A2 = ca1s + ((tt * 2 + li) * 64 + (r0 + fr)) * 1024 + ks * 8;
#pragma unroll
      for (int kk = 0; kk < 16; ++kk) {
        ar[kk]      = *(const bf16x8*)(A2 + kk * 32);
        ar[16 + kk] = *(const bf16x8*)(A2 + 512 + kk * 32);
      }
      if (li == 1) {                       // also bulk-issue the G3 panel loads
        const short* A3 = ca1s + ((tt * 2) * 64 + (r0 + fr)) * 1024 + ks * 8;
#pragma unroll
        for (int kk = 0; kk < 16; ++kk) {
          ar3[kk]      = *(const bf16x8*)(A3 + kk * 32);
          ar3[16 + kk] = *(const bf16x8*)(A3 + 512 + kk * 32);
        }
      }
      __builtin_amdgcn_sched_barrier(0);
      f32x4 p0 = {0.f,0.f,0.f,0.f}, p1 = {0.f,0.f,0.f,0.f};
#pragma unroll
      for (int kk = 0; kk < 16; ++kk) {
        p0 = MFMA16(ar[kk],      *(const bf16x8*)(B2 + ((kk * 32 + ks * 8) ^ xsw)),       p0);
        p1 = MFMA16(ar[16 + kk], *(const bf16x8*)(B2 + ((512 + kk * 32 + ks * 8) ^ xsw)), p1);
      }
      f32x4 g2 = p0 + p1;

      f32x4 xin;
      if (li == 1) {
        f32x4 q0 = {0.f,0.f,0.f,0.f}, q1 = {0.f,0.f,0.f,0.f};
#pragma unroll
        for (int kk = 0; kk < 16; ++kk) {
          q0 = MFMA16(ar3[kk],      *(const bf16x8*)(B3 + ((kk * 32 + ks * 8) ^ xsw)),       q0);
          q1 = MFMA16(ar3[16 + kk], *(const bf16x8*)(B3 + ((512 + kk * 32 + ks * 8) ^ xsw)), q1);
        }
        f32x4 q = q0 + q1;
#pragma unroll
        for (int r = 0; r < 4; ++r) xin[r] = q[r] + ib0;
      } else {
#pragma unroll
        for (int r = 0; r < 4; ++r) xin[r] = cueq[r];
      }

#pragma unroll
      for (int r = 0; r < 4; ++r) {
        int grow = r0 + ks * 4 + r;
        float raw = e5r[r] + g2[r] + e5b;            // 10*TS == 1.0f exactly
        float e5 = 0.69f + 0.3f * sigm(4.0f * (raw - 0.3f));
        e5r[r] = e5;
        float e3 = e5 * e3r[r] + 0.6f * xin[r];
        e3r[r] = e3;
        unsigned my = f2bfu(e3);
        unsigned pr = (unsigned)__shfl_xor((int)my, 1);
        if ((fr & 1) == 0)
          AST(ec3su + ((tt * 2 + li) * 64 + grow) * 512 + ((c0 + fr) >> 1), my | (pr << 16));
        if (grow == 0) {
          out[OUT_E5 + (li * Tn + t) * 1024 + ccol] = e5;
          out[OUT_E3 + (li * Tn + t) * 1024 + ccol] = e3;
        }
      }
    }
    gridbar(flags, (++nb) * 128u);
  }

  // spill fp32 state for next chunk (dispatch boundary provides coherence)
#pragma unroll
  for (int r = 0; r < 4; ++r) {
    int sidx = li * 65536 + (r0 + ks * 4 + r) * 1024 + ccol;
    ec5f[sidx] = e5r[r];
    ec3f[sidx] = e3r[r];
  }
}

__global__ void act_cell(const float* __restrict__ ca1l, const float* __restrict__ wca1act,
                         const float* __restrict__ actbias, float* __restrict__ out) {
  int tid = threadIdx.x;
  if (tid < 128) {
    int b = tid >> 1, a = tid & 1;
    float s = 0.0f;
    for (int k = 0; k < 1024; ++k) s += ca1l[b * 1024 + k] * wca1act[k * 2 + a];
    out[b * 2 + a] = s + actbias[a];
  }
}

extern "C" void kernel_launch(void* const* d_in, const int* in_sizes, int n_in,
                              void* d_out, int out_size, void* d_ws, size_t ws_size,
                              hipStream_t stream) {
  (void)in_sizes; (void)n_in; (void)out_size; (void)ws_size;
  const float* cue      = (const float*)d_in[0];
  const float* ec3_last = (const float*)d_in[1];
  const float* ec5_last = (const float*)d_in[2];
  const float* wca3ca1  = (const float*)d_in[4];
  const float* wec3ca1  = (const float*)d_in[5];
  const float* wca1ec5  = (const float*)d_in[6];
  const float* ca1bias  = (const float*)d_in[7];
  const float* ec5bias  = (const float*)d_in[8];
  const float* inter_w  = (const float*)d_in[9];
  const float* inter_b  = (const float*)d_in[10];
  const float* wca1act  = (const float*)d_in[11];
  const float* actbias  = (const float*)d_in[12];
  float* out = (float*)d_out;

  char* ws = (char*)d_ws;
  unsigned* flags = (unsigned*)(ws + WS_FLAGS);
  short* ec3s = (short*)(ws + WS_EC3S);
  short* ca1s = (short*)(ws + WS_CA1S);
  float* ec5f = (float*)(ws + WS_EC5F);
  float* ec3f = (float*)(ws + WS_EC3F);
  float* ca1l = (float*)(ws + WS_CA1L);
  short* stab = (short*)(ws + WS_S);
  short* w1t  = (short*)(ws + WS_W1T);
  short* w2t  = (short*)(ws + WS_W2T);
  short* w3t  = (short*)(ws + WS_W3T);

  prep_state<<<dim3(512), dim3(256), 0, stream>>>(ec3_last, ec5_last, flags,
                                                  (unsigned*)ec3s, ec5f, ec3f);
  prep_wt<<<dim3(1024), dim3(256), 0, stream>>>(wec3ca1, wca1ec5, w1t, w2t);
  prep_w3<<<dim3(4096), dim3(256), 0, stream>>>(inter_w, w3t);
  prep_ca3<<<dim3(1024), dim3(256), 0, stream>>>(wca3ca1, stab);

  hipFuncSetAttribute((const void*)stepchunk,
                      hipFuncAttributeMaxDynamicSharedMemorySize, 98304);

  for (int c = 0; c < Tn / CHUNK; ++c) {
    stepchunk<<<dim3(128), dim3(256), 98304, stream>>>(
        cue, w1t, w2t, w3t, stab, ca1bias, ec5bias, inter_b,
        flags, ec3s, ca1s, ec5f, ec3f, ca1l, out, c * CHUNK, c * 2 * CHUNK);
  }

  act_cell<<<dim3(1), dim3(128), 0, stream>>>(ca1l, wca1act, actbias, out);
}

// Round 9
// 9622.461 us; speedup vs baseline: 2.8561x; 1.1200x over previous
//
#include <hip/hip_runtime.h>

#define Lnum 2
#define BSn  64
#define Tn   512
#define ECn  1024
#define CA1n 1024
#define CHUNK 16

typedef short bf16x8 __attribute__((ext_vector_type(8)));
typedef float f32x4  __attribute__((ext_vector_type(4)));

#define MFMA16(a,b,c) __builtin_amdgcn_mfma_f32_16x16x32_bf16((a),(b),(c),0,0,0)

// d_out layout: [actCell 64*2][ec3his 2*512*1024][ec5his ...][ca1his ...]
#define OUT_E3  128
#define OUT_E5  (128 + Lnum*Tn*ECn)
#define OUT_CA1 (128 + 2*Lnum*Tn*ECn)

// ws layout (bytes)
#define WS_FLAGS 0                      // sentA[128] @ 0, sentB[128] @ +512B
#define WS_EC3S  8192                   // bf16 [16 slot][2 L][64][1024] = 4MB
#define WS_CA1S  4202496                // bf16 [16 slot][2 L][64][1024] = 4MB
#define WS_EC5F  8396800                // f32 [2][64][1024]
#define WS_EC3F  8921088                // f32 [2][64][1024]
#define WS_CA1L  9445376                // f32 [64][1024]
#define WS_S     9707520                // bf16 [2][512][1024]
#define WS_W1T   11804672               // bf16 [2][1024c][1024k]
#define WS_W2T   15998976               // bf16 [2][1024e][1024k]
#define WS_W3T   20193280               // bf16 [1024e][1024k]  (ends ~22.3MB)

#define AST(p, v) __hip_atomic_store((p), (v), __ATOMIC_RELAXED, __HIP_MEMORY_SCOPE_AGENT)
#define ALD(p)    __hip_atomic_load((p), __ATOMIC_RELAXED, __HIP_MEMORY_SCOPE_AGENT)

__device__ __forceinline__ float sigm(float x) { return 1.0f / (1.0f + __expf(-x)); }

__device__ __forceinline__ unsigned f2bfu(float f) {
  unsigned u = __float_as_uint(f);
  u += 0x7fffu + ((u >> 16) & 1u);   // RNE
  return u >> 16;
}
__device__ __forceinline__ short f2bf(float f) { return (short)f2bfu(f); }
__device__ __forceinline__ float bf2f(short s) {
  return __uint_as_float(((unsigned)(unsigned short)s) << 16);
}

// ---- dependency sentinels (replace global barrier) ----
// Poll: all waves spin on a 64-lane sc1 load of the producer set's sentinels.
__device__ __forceinline__ void pollGE(const unsigned* s, unsigned need) {
  const int lane = threadIdx.x & 63;
  while (__any(ALD(&s[lane]) < need)) {}
  __builtin_amdgcn_sched_barrier(0);
  asm volatile("" ::: "memory");
}
// Publish: drain this block's sc1 data stores, then tid0 posts the sentinel.
__device__ __forceinline__ void publish(unsigned* s, int bid, unsigned val) {
  asm volatile("s_waitcnt vmcnt(0)" ::: "memory");  // stores acked at IF$
  __syncthreads();                                  // all 4 waves drained
  if (threadIdx.x == 0) AST(&s[bid], val);
}

// ---------------- prep kernels (R4-R8 proven) ----------------

__global__ void prep_state(const float* __restrict__ ec3_last,
                           const float* __restrict__ ec5_last,
                           unsigned* __restrict__ flags, unsigned* __restrict__ ec3su,
                           float* __restrict__ ec5f, float* __restrict__ ec3f) {
  int i = blockIdx.x * blockDim.x + threadIdx.x;   // 512*256 = 131072
  if (i < 2048) flags[i] = 0u;
  float v3 = ec3_last[i];
  ec3f[i] = v3;
  ec5f[i] = ec5_last[i];
  if (i < Lnum * BSn * 512) {      // pack initial ec3 into slot 15
    float lo = ec3_last[2 * i], hi = ec3_last[2 * i + 1];
    ec3su[15 * 65536 + i] = f2bfu(lo) | (f2bfu(hi) << 16);
  }
}

// 64x64 LDS tile transpose fp32[k][c] -> bf16[c][k], for W1 (m=0) and W2 (m=1)
__global__ void prep_wt(const float* __restrict__ w1, const float* __restrict__ w2,
                        short* __restrict__ w1t, short* __restrict__ w2t) {
  __shared__ float tile[64][65];
  const int b = blockIdx.x;               // 1024 = 2 mats * 2 layers * 16*16 tiles
  const int m  = b >> 9;
  const int li = (b >> 8) & 1;
  const int kt = (b >> 4) & 15;
  const int ct = b & 15;
  const float* src = (m == 0 ? w1 : w2) + li * (1024 * 1024);
  short* dst = (m == 0 ? w1t : w2t) + li * (1024 * 1024);
#pragma unroll
  for (int i = 0; i < 16; ++i) {
    int idx = threadIdx.x + i * 256;
    int r = idx >> 6, c = idx & 63;
    tile[r][c] = src[(kt * 64 + r) * 1024 + ct * 64 + c];
  }
  __syncthreads();
#pragma unroll
  for (int i = 0; i < 16; ++i) {
    int idx = threadIdx.x + i * 256;
    int c = idx >> 6, r = idx & 63;
    dst[(ct * 64 + c) * 1024 + kt * 64 + r] = f2bf(tile[r][c]);
  }
}

__global__ void prep_w3(const float* __restrict__ inter_w, short* __restrict__ w3t) {
  int i = blockIdx.x * blockDim.x + threadIdx.x;   // 4096*256 = 1048576
  w3t[i] = f2bf(inter_w[i]);                        // layer 0, already [e][k]
}

__global__ void prep_ca3(const float* __restrict__ wca3ca1, short* __restrict__ S) {
  const int t = blockIdx.x >> 1, li = blockIdx.x & 1;
  __shared__ float gauss[192];
  const float stepc = 512.0f / 1023.0f;
  const float tf = (float)t;
  int kmin = (int)floorf((tf - 40.0f) / stepc) - 1; if (kmin < 0) kmin = 0;
  int kmax = (int)ceilf((tf + 40.0f) / stepc) + 1;  if (kmax > 1023) kmax = 1023;
  int nw = kmax - kmin + 1;
  for (int j = threadIdx.x; j < nw; j += 256) {
    float d = (float)(kmin + j) * stepc - tf;
    gauss[j] = __expf(-d * d * 0.02f);
  }
  __syncthreads();
  const float* W = wca3ca1 + li * (1024 * 1024);
  for (int c = threadIdx.x; c < 1024; c += 256) {
    float s = 0.0f;
    for (int j = 0; j < nw; ++j) s += gauss[j] * W[(kmin + j) * 1024 + c];
    S[(li * Tn + t) * 1024 + c] = f2bf(sigm(10.0f * (s - 0.5f)));
  }
}

// ---------------- 16-step chunk kernel ----------------
// grid 128 = [li:1][ctile:6], block 256 = 4 waves; wave w -> rows w*16..w*16+15
// Sync: per-block sentinels on true dependencies only. Layer-0's serial loop
// never waits on layer-1; layer-1 trails one phase. Slot rotation bounds
// intra-dispatch skew (<=15 steps < 16 slots). Sentinels are absolute-step,
// monotonic across chunks (dispatch boundary resets caches, not sentinels).
__global__ void __launch_bounds__(256, 1) stepchunk(
    const float* __restrict__ cue,
    const short* __restrict__ w1t, const short* __restrict__ w2t,
    const short* __restrict__ w3t, const short* __restrict__ stab,
    const float* __restrict__ ca1bias, const float* __restrict__ ec5bias,
    const float* __restrict__ interb,
    unsigned* __restrict__ flags, short* __restrict__ ec3s,
    short* __restrict__ ca1s, float* __restrict__ ec5f, float* __restrict__ ec3f,
    float* __restrict__ ca1l, float* __restrict__ out, int t0) {
  extern __shared__ short lds[];
  short* BT1 = lds;             // [16c][1024k] swizzled: idx = c*1024 + (k ^ ((c&7)<<3))
  short* BT2 = lds + 16 * 1024;
  short* BT3 = lds + 32 * 1024;

  unsigned* sentA = flags;          // [128]
  unsigned* sentB = flags + 128;    // [128]
  unsigned* ec3su = (unsigned*)ec3s;
  unsigned* ca1su = (unsigned*)ca1s;

  const int b = blockIdx.x;
  const int li = b >> 6;
  const int c0 = (b & 63) << 4;
  const int tid = threadIdx.x;
  const int lane = tid & 63, wave = tid >> 6;
  const int fr = lane & 15, ks = lane >> 4;
  const int r0 = wave << 4;
  const int ccol = c0 + fr;

  // ---- stage weight slices into LDS once per chunk
  {
    int cp = tid & 15;
    int k0 = (tid >> 4) << 6;
    int xm = (cp & 7) << 3;
    const short* s1 = w1t + li * 1048576 + (c0 + cp) * 1024;
    const short* s2 = w2t + li * 1048576 + (c0 + cp) * 1024;
#pragma unroll
    for (int j = 0; j < 8; ++j) {
      int k = k0 + j * 8;
      *(bf16x8*)(BT1 + cp * 1024 + (k ^ xm)) = *(const bf16x8*)(s1 + k);
      *(bf16x8*)(BT2 + cp * 1024 + (k ^ xm)) = *(const bf16x8*)(s2 + k);
    }
    if (li == 1) {
      const short* s3 = w3t + (c0 + cp) * 1024;
#pragma unroll
      for (int j = 0; j < 8; ++j) {
        int k = k0 + j * 8;
        *(bf16x8*)(BT3 + cp * 1024 + (k ^ xm)) = *(const bf16x8*)(s3 + k);
      }
    }
  }
  __syncthreads();

  const int xsw = (fr & 7) << 3;
  const short* B1 = BT1 + fr * 1024;
  const short* B2 = BT2 + fr * 1024;
  const short* B3 = BT3 + fr * 1024;

  const float cb  = ca1bias[li * 1024 + ccol];
  const float e5b = ec5bias[li * 1024 + ccol];
  const float ib0 = interb[1024 + ccol];    // layer-1 inter_b (used when li==1)

  // block-exclusive fp32 state -> registers for the chunk
  float e5r[4], e3r[4];
#pragma unroll
  for (int r = 0; r < 4; ++r) {
    int sidx = li * 65536 + (r0 + ks * 4 + r) * 1024 + ccol;
    e5r[r] = ec5f[sidx];
    e3r[r] = ec3f[sidx];
  }

  bf16x8 ar[32], ar3[32];

  for (int tt = 0; tt < CHUNK; ++tt) {
    const int t = t0 + tt;
    const int rd = (tt + 15) & 15;   // ec3 slot written last step (15 = initial/prev)

    float cueq[4];
    if (li == 0) {                        // prefetch cue (read-only; overlaps poll)
#pragma unroll
      for (int r = 0; r < 4; ++r)
        cueq[r] = cue[((r0 + ks * 4 + r) * Tn + t) * 1024 + ccol];
    }

    // ---------- phase A: ca1 = relu(S * (1 + 3*sig(ec3@W1)) - bias) ----------
    {
      pollGE(sentB + li * 64, (unsigned)t);   // my layer's ec3[t-1] published
      const short* A1 = ec3s + ((rd * 2 + li) * 64 + (r0 + fr)) * 1024 + ks * 8;
#pragma unroll
      for (int kk = 0; kk < 16; ++kk) {
        ar[kk]      = *(const bf16x8*)(A1 + kk * 32);
        ar[16 + kk] = *(const bf16x8*)(A1 + 512 + kk * 32);
      }
      __builtin_amdgcn_sched_barrier(0);   // bulk-issue all 32 loads first
      f32x4 a0 = {0.f,0.f,0.f,0.f}, a1 = {0.f,0.f,0.f,0.f};
#pragma unroll
      for (int kk = 0; kk < 16; ++kk) {
        a0 = MFMA16(ar[kk],      *(const bf16x8*)(B1 + ((kk * 32 + ks * 8) ^ xsw)),       a0);
        a1 = MFMA16(ar[16 + kk], *(const bf16x8*)(B1 + ((512 + kk * 32 + ks * 8) ^ xsw)), a1);
      }
      f32x4 acc = a0 + a1;
      const float g = bf2f(stab[(li * Tn + t) * 1024 + ccol]);
#pragma unroll
      for (int r = 0; r < 4; ++r) {
        int grow = r0 + ks * 4 + r;
        float cv = fmaxf(g * (1.0f + 3.0f * sigm(acc[r])) - cb, 0.0f);
        unsigned my = f2bfu(cv);
        unsigned pr = (unsigned)__shfl_xor((int)my, 1);
        if ((fr & 1) == 0)
          AST(ca1su + ((tt * 2 + li) * 64 + grow) * 512 + ((c0 + fr) >> 1), my | (pr << 16));
        if (grow == 0) out[OUT_CA1 + (li * Tn + t) * 1024 + ccol] = cv;
        if (t == Tn - 1 && li == 1) ca1l[grow * 1024 + ccol] = cv;
      }
      publish(sentA, b, (unsigned)(t + 1));
    }

    // ---------- phase B: ec5/ec3 update ----------
    {
      pollGE(sentA + li * 64, (unsigned)(t + 1));   // my layer's ca1[t]
      if (li == 1) pollGE(sentA, (unsigned)(t + 1)); // plus layer-0's ca1[t]
      const short* A2 = ca1s + ((tt * 2 + li) * 64 + (r0 + fr)) * 1024 + ks * 8;
#pragma unroll
      for (int kk = 0; kk < 16; ++kk) {
        ar[kk]      = *(const bf16x8*)(A2 + kk * 32);
        ar[16 + kk] = *(const bf16x8*)(A2 + 512 + kk * 32);
      }
      if (li == 1) {                       // also bulk-issue the G3 panel loads
        const short* A3 = ca1s + ((tt * 2) * 64 + (r0 + fr)) * 1024 + ks * 8;
#pragma unroll
        for (int kk = 0; kk < 16; ++kk) {
          ar3[kk]      = *(const bf16x8*)(A3 + kk * 32);
          ar3[16 + kk] = *(const bf16x8*)(A3 + 512 + kk * 32);
        }
      }
      __builtin_amdgcn_sched_barrier(0);
      f32x4 p0 = {0.f,0.f,0.f,0.f}, p1 = {0.f,0.f,0.f,0.f};
#pragma unroll
      for (int kk = 0; kk < 16; ++kk) {
        p0 = MFMA16(ar[kk],      *(const bf16x8*)(B2 + ((kk * 32 + ks * 8) ^ xsw)),       p0);
        p1 = MFMA16(ar[16 + kk], *(const bf16x8*)(B2 + ((512 + kk * 32 + ks * 8) ^ xsw)), p1);
      }
      f32x4 g2 = p0 + p1;

      f32x4 xin;
      if (li == 1) {
        f32x4 q0 = {0.f,0.f,0.f,0.f}, q1 = {0.f,0.f,0.f,0.f};
#pragma unroll
        for (int kk = 0; kk < 16; ++kk) {
          q0 = MFMA16(ar3[kk],      *(const bf16x8*)(B3 + ((kk * 32 + ks * 8) ^ xsw)),       q0);
          q1 = MFMA16(ar3[16 + kk], *(const bf16x8*)(B3 + ((512 + kk * 32 + ks * 8) ^ xsw)), q1);
        }
        f32x4 q = q0 + q1;
#pragma unroll
        for (int r = 0; r < 4; ++r) xin[r] = q[r] + ib0;
      } else {
#pragma unroll
        for (int r = 0; r < 4; ++r) xin[r] = cueq[r];
      }

#pragma unroll
      for (int r = 0; r < 4; ++r) {
        int grow = r0 + ks * 4 + r;
        float raw = e5r[r] + g2[r] + e5b;            // 10*TS == 1.0f exactly
        float e5 = 0.69f + 0.3f * sigm(4.0f * (raw - 0.3f));
        e5r[r] = e5;
        float e3 = e5 * e3r[r] + 0.6f * xin[r];
        e3r[r] = e3;
        unsigned my = f2bfu(e3);
        unsigned pr = (unsigned)__shfl_xor((int)my, 1);
        if ((fr & 1) == 0)
          AST(ec3su + ((tt * 2 + li) * 64 + grow) * 512 + ((c0 + fr) >> 1), my | (pr << 16));
        if (grow == 0) {
          out[OUT_E5 + (li * Tn + t) * 1024 + ccol] = e5;
          out[OUT_E3 + (li * Tn + t) * 1024 + ccol] = e3;
        }
      }
      publish(sentB, b, (unsigned)(t + 1));
    }
  }

  // spill fp32 state for next chunk (dispatch boundary provides coherence)
#pragma unroll
  for (int r = 0; r < 4; ++r) {
    int sidx = li * 65536 + (r0 + ks * 4 + r) * 1024 + ccol;
    ec5f[sidx] = e5r[r];
    ec3f[sidx] = e3r[r];
  }
}

__global__ void act_cell(const float* __restrict__ ca1l, const float* __restrict__ wca1act,
                         const float* __restrict__ actbias, float* __restrict__ out) {
  int tid = threadIdx.x;
  if (tid < 128) {
    int b = tid >> 1, a = tid & 1;
    float s = 0.0f;
    for (int k = 0; k < 1024; ++k) s += ca1l[b * 1024 + k] * wca1act[k * 2 + a];
    out[b * 2 + a] = s + actbias[a];
  }
}

extern "C" void kernel_launch(void* const* d_in, const int* in_sizes, int n_in,
                              void* d_out, int out_size, void* d_ws, size_t ws_size,
                              hipStream_t stream) {
  (void)in_sizes; (void)n_in; (void)out_size; (void)ws_size;
  const float* cue      = (const float*)d_in[0];
  const float* ec3_last = (const float*)d_in[1];
  const float* ec5_last = (const float*)d_in[2];
  const float* wca3ca1  = (const float*)d_in[4];
  const float* wec3ca1  = (const float*)d_in[5];
  const float* wca1ec5  = (const float*)d_in[6];
  const float* ca1bias  = (const float*)d_in[7];
  const float* ec5bias  = (const float*)d_in[8];
  const float* inter_w  = (const float*)d_in[9];
  const float* inter_b  = (const float*)d_in[10];
  const float* wca1act  = (const float*)d_in[11];
  const float* actbias  = (const float*)d_in[12];
  float* out = (float*)d_out;

  char* ws = (char*)d_ws;
  unsigned* flags = (unsigned*)(ws + WS_FLAGS);
  short* ec3s = (short*)(ws + WS_EC3S);
  short* ca1s = (short*)(ws + WS_CA1S);
  float* ec5f = (float*)(ws + WS_EC5F);
  float* ec3f = (float*)(ws + WS_EC3F);
  float* ca1l = (float*)(ws + WS_CA1L);
  short* stab = (short*)(ws + WS_S);
  short* w1t  = (short*)(ws + WS_W1T);
  short* w2t  = (short*)(ws + WS_W2T);
  short* w3t  = (short*)(ws + WS_W3T);

  prep_state<<<dim3(512), dim3(256), 0, stream>>>(ec3_last, ec5_last, flags,
                                                  (unsigned*)ec3s, ec5f, ec3f);
  prep_wt<<<dim3(1024), dim3(256), 0, stream>>>(wec3ca1, wca1ec5, w1t, w2t);
  prep_w3<<<dim3(4096), dim3(256), 0, stream>>>(inter_w, w3t);
  prep_ca3<<<dim3(1024), dim3(256), 0, stream>>>(wca3ca1, stab);

  hipFuncSetAttribute((const void*)stepchunk,
                      hipFuncAttributeMaxDynamicSharedMemorySize, 98304);

  for (int c = 0; c < Tn / CHUNK; ++c) {
    stepchunk<<<dim3(128), dim3(256), 98304, stream>>>(
        cue, w1t, w2t, w3t, stab, ca1bias, ec5bias, inter_b,
        flags, ec3s, ca1s, ec5f, ec3f, ca1l, out, c * CHUNK);
  }

  act_cell<<<dim3(1), dim3(128), 0, stream>>>(ca1l, wca1act, actbias, out);
}

// Round 10
// 8964.562 us; speedup vs baseline: 3.0657x; 1.0734x over previous
//
#include <hip/hip_runtime.h>

#define Lnum 2
#define BSn  64
#define Tn   512
#define ECn  1024
#define CA1n 1024
#define CHUNK 16

typedef short bf16x8 __attribute__((ext_vector_type(8)));
typedef float f32x4  __attribute__((ext_vector_type(4)));

#define MFMA16(a,b,c) __builtin_amdgcn_mfma_f32_16x16x32_bf16((a),(b),(c),0,0,0)

// d_out layout: [actCell 64*2][ec3his 2*512*1024][ec5his ...][ca1his ...]
#define OUT_E3  128
#define OUT_E5  (128 + Lnum*Tn*ECn)
#define OUT_CA1 (128 + 2*Lnum*Tn*ECn)

// ws layout (bytes)
#define WS_FLAGS 0                      // sentA[128] @ 0, sentB[128] @ +512B
#define WS_EC3S  8192                   // bf16 [16 slot][2 L][64][1024] = 4MB
#define WS_CA1S  4202496                // bf16 [16 slot][2 L][64][1024] = 4MB
#define WS_EC5F  8396800                // f32 [2][64][1024]
#define WS_EC3F  8921088                // f32 [2][64][1024]
#define WS_CA1L  9445376                // f32 [64][1024]
#define WS_S     9707520                // bf16 [2][512][1024]
#define WS_W1T   11804672               // bf16 [2][1024c][1024k]
#define WS_W2T   15998976               // bf16 [2][1024e][1024k]
#define WS_W3T   20193280               // bf16 [1024e][1024k]  (ends ~22.3MB)

#define AST(p, v) __hip_atomic_store((p), (v), __ATOMIC_RELAXED, __HIP_MEMORY_SCOPE_AGENT)
#define ALD(p)    __hip_atomic_load((p), __ATOMIC_RELAXED, __HIP_MEMORY_SCOPE_AGENT)

__device__ __forceinline__ float sigm(float x) { return 1.0f / (1.0f + __expf(-x)); }

__device__ __forceinline__ unsigned f2bfu(float f) {
  unsigned u = __float_as_uint(f);
  u += 0x7fffu + ((u >> 16) & 1u);   // RNE
  return u >> 16;
}
__device__ __forceinline__ short f2bf(float f) { return (short)f2bfu(f); }
__device__ __forceinline__ float bf2f(short s) {
  return __uint_as_float(((unsigned)(unsigned short)s) << 16);
}

// ---- dependency sentinels: WAVE-0-ONLY paced polls (others park at s_barrier) ----
__device__ __forceinline__ void pollOne(const unsigned* s, unsigned need) {
  const int lane = threadIdx.x & 63;
  while (__any(ALD(&s[lane]) < need)) __builtin_amdgcn_s_sleep(2);
  __builtin_amdgcn_sched_barrier(0);
  asm volatile("" ::: "memory");
}
__device__ __forceinline__ void pollTwo(const unsigned* s, unsigned need) {
  const int lane = threadIdx.x & 63;
  while (__any((ALD(&s[lane]) < need) | (ALD(&s[64 + lane]) < need)))
    __builtin_amdgcn_s_sleep(2);
  __builtin_amdgcn_sched_barrier(0);
  asm volatile("" ::: "memory");
}
// Publish: drain own sc1 slot stores, then tid0 posts the sentinel.
__device__ __forceinline__ void publish(unsigned* s, int bid, unsigned val) {
  asm volatile("s_waitcnt vmcnt(0)" ::: "memory");
  __syncthreads();
  if (threadIdx.x == 0) AST(&s[bid], val);
}

// ---------------- prep kernels (R4-R9 proven) ----------------

__global__ void prep_state(const float* __restrict__ ec3_last,
                           const float* __restrict__ ec5_last,
                           unsigned* __restrict__ flags, unsigned* __restrict__ ec3su,
                           float* __restrict__ ec5f, float* __restrict__ ec3f) {
  int i = blockIdx.x * blockDim.x + threadIdx.x;   // 512*256 = 131072
  if (i < 2048) flags[i] = 0u;
  float v3 = ec3_last[i];
  ec3f[i] = v3;
  ec5f[i] = ec5_last[i];
  if (i < Lnum * BSn * 512) {      // pack initial ec3 into slot 15
    float lo = ec3_last[2 * i], hi = ec3_last[2 * i + 1];
    ec3su[15 * 65536 + i] = f2bfu(lo) | (f2bfu(hi) << 16);
  }
}

// 64x64 LDS tile transpose fp32[k][c] -> bf16[c][k], for W1 (m=0) and W2 (m=1)
__global__ void prep_wt(const float* __restrict__ w1, const float* __restrict__ w2,
                        short* __restrict__ w1t, short* __restrict__ w2t) {
  __shared__ float tile[64][65];
  const int b = blockIdx.x;               // 1024 = 2 mats * 2 layers * 16*16 tiles
  const int m  = b >> 9;
  const int li = (b >> 8) & 1;
  const int kt = (b >> 4) & 15;
  const int ct = b & 15;
  const float* src = (m == 0 ? w1 : w2) + li * (1024 * 1024);
  short* dst = (m == 0 ? w1t : w2t) + li * (1024 * 1024);
#pragma unroll
  for (int i = 0; i < 16; ++i) {
    int idx = threadIdx.x + i * 256;
    int r = idx >> 6, c = idx & 63;
    tile[r][c] = src[(kt * 64 + r) * 1024 + ct * 64 + c];
  }
  __syncthreads();
#pragma unroll
  for (int i = 0; i < 16; ++i) {
    int idx = threadIdx.x + i * 256;
    int c = idx >> 6, r = idx & 63;
    dst[(ct * 64 + c) * 1024 + kt * 64 + r] = f2bf(tile[r][c]);
  }
}

__global__ void prep_w3(const float* __restrict__ inter_w, short* __restrict__ w3t) {
  int i = blockIdx.x * blockDim.x + threadIdx.x;   // 4096*256 = 1048576
  w3t[i] = f2bf(inter_w[i]);                        // layer 0, already [e][k]
}

__global__ void prep_ca3(const float* __restrict__ wca3ca1, short* __restrict__ S) {
  const int t = blockIdx.x >> 1, li = blockIdx.x & 1;
  __shared__ float gauss[192];
  const float stepc = 512.0f / 1023.0f;
  const float tf = (float)t;
  int kmin = (int)floorf((tf - 40.0f) / stepc) - 1; if (kmin < 0) kmin = 0;
  int kmax = (int)ceilf((tf + 40.0f) / stepc) + 1;  if (kmax > 1023) kmax = 1023;
  int nw = kmax - kmin + 1;
  for (int j = threadIdx.x; j < nw; j += 256) {
    float d = (float)(kmin + j) * stepc - tf;
    gauss[j] = __expf(-d * d * 0.02f);
  }
  __syncthreads();
  const float* W = wca3ca1 + li * (1024 * 1024);
  for (int c = threadIdx.x; c < 1024; c += 256) {
    float s = 0.0f;
    for (int j = 0; j < nw; ++j) s += gauss[j] * W[(kmin + j) * 1024 + c];
    S[(li * Tn + t) * 1024 + c] = f2bf(sigm(10.0f * (s - 0.5f)));
  }
}

// ---------------- 16-step chunk kernel ----------------
// grid 128 = [li:1][ctile:6], block 256 = 4 waves; wave w -> rows w*16..w*16+15
// Sync: per-block sentinels, wave-0-only paced polls. Critical-path hygiene:
// cue prefetch and history stores are kept OUT of the vmcnt(0) publish drains.
__global__ void __launch_bounds__(256, 1) stepchunk(
    const float* __restrict__ cue,
    const short* __restrict__ w1t, const short* __restrict__ w2t,
    const short* __restrict__ w3t, const short* __restrict__ stab,
    const float* __restrict__ ca1bias, const float* __restrict__ ec5bias,
    const float* __restrict__ interb,
    unsigned* __restrict__ flags, short* __restrict__ ec3s,
    short* __restrict__ ca1s, float* __restrict__ ec5f, float* __restrict__ ec3f,
    float* __restrict__ ca1l, float* __restrict__ out, int t0) {
  extern __shared__ short lds[];
  short* BT1 = lds;             // [16c][1024k] swizzled: idx = c*1024 + (k ^ ((c&7)<<3))
  short* BT2 = lds + 16 * 1024;
  short* BT3 = lds + 32 * 1024;

  unsigned* sentA = flags;          // [128]
  unsigned* sentB = flags + 128;    // [128]
  unsigned* ec3su = (unsigned*)ec3s;
  unsigned* ca1su = (unsigned*)ca1s;

  const int b = blockIdx.x;
  const int li = b >> 6;
  const int c0 = (b & 63) << 4;
  const int tid = threadIdx.x;
  const int lane = tid & 63, wave = tid >> 6;
  const int fr = lane & 15, ks = lane >> 4;
  const int r0 = wave << 4;
  const int ccol = c0 + fr;

  // ---- stage weight slices into LDS once per chunk
  {
    int cp = tid & 15;
    int k0 = (tid >> 4) << 6;
    int xm = (cp & 7) << 3;
    const short* s1 = w1t + li * 1048576 + (c0 + cp) * 1024;
    const short* s2 = w2t + li * 1048576 + (c0 + cp) * 1024;
#pragma unroll
    for (int j = 0; j < 8; ++j) {
      int k = k0 + j * 8;
      *(bf16x8*)(BT1 + cp * 1024 + (k ^ xm)) = *(const bf16x8*)(s1 + k);
      *(bf16x8*)(BT2 + cp * 1024 + (k ^ xm)) = *(const bf16x8*)(s2 + k);
    }
    if (li == 1) {
      const short* s3 = w3t + (c0 + cp) * 1024;
#pragma unroll
      for (int j = 0; j < 8; ++j) {
        int k = k0 + j * 8;
        *(bf16x8*)(BT3 + cp * 1024 + (k ^ xm)) = *(const bf16x8*)(s3 + k);
      }
    }
  }
  __syncthreads();

  const int xsw = (fr & 7) << 3;
  const short* B1 = BT1 + fr * 1024;
  const short* B2 = BT2 + fr * 1024;
  const short* B3 = BT3 + fr * 1024;

  const float cb  = ca1bias[li * 1024 + ccol];
  const float e5b = ec5bias[li * 1024 + ccol];
  const float ib0 = interb[1024 + ccol];    // layer-1 inter_b (used when li==1)

  // block-exclusive fp32 state -> registers for the chunk
  float e5r[4], e3r[4];
#pragma unroll
  for (int r = 0; r < 4; ++r) {
    int sidx = li * 65536 + (r0 + ks * 4 + r) * 1024 + ccol;
    e5r[r] = ec5f[sidx];
    e3r[r] = ec3f[sidx];
  }

  bf16x8 ar[32], ar3[32];

  for (int tt = 0; tt < CHUNK; ++tt) {
    const int t = t0 + tt;
    const int rd = (tt + 15) & 15;   // ec3 slot written last step (15 = initial/prev)

    // ---------- phase A: ca1 = relu(S * (1 + 3*sig(ec3@W1)) - bias) ----------
    f32x4 cvv;
    {
      if (wave == 0) pollOne(sentB + li * 64, (unsigned)t);
      __syncthreads();
      const short* A1 = ec3s + ((rd * 2 + li) * 64 + (r0 + fr)) * 1024 + ks * 8;
#pragma unroll
      for (int kk = 0; kk < 16; ++kk) {
        ar[kk]      = *(const bf16x8*)(A1 + kk * 32);
        ar[16 + kk] = *(const bf16x8*)(A1 + 512 + kk * 32);
      }
      __builtin_amdgcn_sched_barrier(0);   // bulk-issue all 32 loads first
      f32x4 a0 = {0.f,0.f,0.f,0.f}, a1 = {0.f,0.f,0.f,0.f};
#pragma unroll
      for (int kk = 0; kk < 16; ++kk) {
        a0 = MFMA16(ar[kk],      *(const bf16x8*)(B1 + ((kk * 32 + ks * 8) ^ xsw)),       a0);
        a1 = MFMA16(ar[16 + kk], *(const bf16x8*)(B1 + ((512 + kk * 32 + ks * 8) ^ xsw)), a1);
      }
      f32x4 acc = a0 + a1;
      const float g = bf2f(stab[(li * Tn + t) * 1024 + ccol]);
#pragma unroll
      for (int r = 0; r < 4; ++r) {
        int grow = r0 + ks * 4 + r;
        float cv = fmaxf(g * (1.0f + 3.0f * sigm(acc[r])) - cb, 0.0f);
        cvv[r] = cv;
        unsigned my = f2bfu(cv);
        unsigned pr = (unsigned)__shfl_xor((int)my, 1);
        if ((fr & 1) == 0)
          AST(ca1su + ((tt * 2 + li) * 64 + grow) * 512 + ((c0 + fr) >> 1), my | (pr << 16));
      }
      publish(sentA, b, (unsigned)(t + 1));   // drain covers ONLY slot stores
      // deferred history writes (off the publish critical path)
#pragma unroll
      for (int r = 0; r < 4; ++r) {
        int grow = r0 + ks * 4 + r;
        if (grow == 0) out[OUT_CA1 + (li * Tn + t) * 1024 + ccol] = cvv[r];
        if (t == Tn - 1 && li == 1) ca1l[grow * 1024 + ccol] = cvv[r];
      }
    }

    // ---------- phase B: ec5/ec3 update ----------
    {
      float cueq[4];
      if (li == 0) {                       // prefetch cue NOW (overlaps the poll)
#pragma unroll
        for (int r = 0; r < 4; ++r)
          cueq[r] = cue[((r0 + ks * 4 + r) * Tn + t) * 1024 + ccol];
      }
      if (wave == 0) {
        if (li == 0) pollOne(sentA, (unsigned)(t + 1));
        else         pollTwo(sentA, (unsigned)(t + 1));
      }
      __syncthreads();
      const short* A2 = ca1s + ((tt * 2 + li) * 64 + (r0 + fr)) * 1024 + ks * 8;
#pragma unroll
      for (int kk = 0; kk < 16; ++kk) {
        ar[kk]      = *(const bf16x8*)(A2 + kk * 32);
        ar[16 + kk] = *(const bf16x8*)(A2 + 512 + kk * 32);
      }
      if (li == 1) {                       // also bulk-issue the G3 panel loads
        const short* A3 = ca1s + ((tt * 2) * 64 + (r0 + fr)) * 1024 + ks * 8;
#pragma unroll
        for (int kk = 0; kk < 16; ++kk) {
          ar3[kk]      = *(const bf16x8*)(A3 + kk * 32);
          ar3[16 + kk] = *(const bf16x8*)(A3 + 512 + kk * 32);
        }
      }
      __builtin_amdgcn_sched_barrier(0);
      f32x4 p0 = {0.f,0.f,0.f,0.f}, p1 = {0.f,0.f,0.f,0.f};
#pragma unroll
      for (int kk = 0; kk < 16; ++kk) {
        p0 = MFMA16(ar[kk],      *(const bf16x8*)(B2 + ((kk * 32 + ks * 8) ^ xsw)),       p0);
        p1 = MFMA16(ar[16 + kk], *(const bf16x8*)(B2 + ((512 + kk * 32 + ks * 8) ^ xsw)), p1);
      }
      f32x4 g2 = p0 + p1;

      f32x4 xin;
      if (li == 1) {
        f32x4 q0 = {0.f,0.f,0.f,0.f}, q1 = {0.f,0.f,0.f,0.f};
#pragma unroll
        for (int kk = 0; kk < 16; ++kk) {
          q0 = MFMA16(ar3[kk],      *(const bf16x8*)(B3 + ((kk * 32 + ks * 8) ^ xsw)),       q0);
          q1 = MFMA16(ar3[16 + kk], *(const bf16x8*)(B3 + ((512 + kk * 32 + ks * 8) ^ xsw)), q1);
        }
        f32x4 q = q0 + q1;
#pragma unroll
        for (int r = 0; r < 4; ++r) xin[r] = q[r] + ib0;
      } else {
#pragma unroll
        for (int r = 0; r < 4; ++r) xin[r] = cueq[r];
      }

#pragma unroll
      for (int r = 0; r < 4; ++r) {
        float raw = e5r[r] + g2[r] + e5b;            // 10*TS == 1.0f exactly
        float e5 = 0.69f + 0.3f * sigm(4.0f * (raw - 0.3f));
        e5r[r] = e5;
        float e3 = e5 * e3r[r] + 0.6f * xin[r];
        e3r[r] = e3;
        int grow = r0 + ks * 4 + r;
        unsigned my = f2bfu(e3);
        unsigned pr = (unsigned)__shfl_xor((int)my, 1);
        if ((fr & 1) == 0)
          AST(ec3su + ((tt * 2 + li) * 64 + grow) * 512 + ((c0 + fr) >> 1), my | (pr << 16));
      }
      publish(sentB, b, (unsigned)(t + 1));   // drain covers ONLY slot stores
      // deferred history writes
#pragma unroll
      for (int r = 0; r < 4; ++r) {
        int grow = r0 + ks * 4 + r;
        if (grow == 0) {
          out[OUT_E5 + (li * Tn + t) * 1024 + ccol] = e5r[r];
          out[OUT_E3 + (li * Tn + t) * 1024 + ccol] = e3r[r];
        }
      }
    }
  }

  // spill fp32 state for next chunk (dispatch boundary provides coherence)
#pragma unroll
  for (int r = 0; r < 4; ++r) {
    int sidx = li * 65536 + (r0 + ks * 4 + r) * 1024 + ccol;
    ec5f[sidx] = e5r[r];
    ec3f[sidx] = e3r[r];
  }
}

__global__ void act_cell(const float* __restrict__ ca1l, const float* __restrict__ wca1act,
                         const float* __restrict__ actbias, float* __restrict__ out) {
  int tid = threadIdx.x;
  if (tid < 128) {
    int b = tid >> 1, a = tid & 1;
    float s = 0.0f;
    for (int k = 0; k < 1024; ++k) s += ca1l[b * 1024 + k] * wca1act[k * 2 + a];
    out[b * 2 + a] = s + actbias[a];
  }
}

extern "C" void kernel_launch(void* const* d_in, const int* in_sizes, int n_in,
                              void* d_out, int out_size, void* d_ws, size_t ws_size,
                              hipStream_t stream) {
  (void)in_sizes; (void)n_in; (void)out_size; (void)ws_size;
  const float* cue      = (const float*)d_in[0];
  const float* ec3_last = (const float*)d_in[1];
  const float* ec5_last = (const float*)d_in[2];
  const float* wca3ca1  = (const float*)d_in[4];
  const float* wec3ca1  = (const float*)d_in[5];
  const float* wca1ec5  = (const float*)d_in[6];
  const float* ca1bias  = (const float*)d_in[7];
  const float* ec5bias  = (const float*)d_in[8];
  const float* inter_w  = (const float*)d_in[9];
  const float* inter_b  = (const float*)d_in[10];
  const float* wca1act  = (const float*)d_in[11];
  const float* actbias  = (const float*)d_in[12];
  float* out = (float*)d_out;

  char* ws = (char*)d_ws;
  unsigned* flags = (unsigned*)(ws + WS_FLAGS);
  short* ec3s = (short*)(ws + WS_EC3S);
  short* ca1s = (short*)(ws + WS_CA1S);
  float* ec5f = (float*)(ws + WS_EC5F);
  float* ec3f = (float*)(ws + WS_EC3F);
  float* ca1l = (float*)(ws + WS_CA1L);
  short* stab = (short*)(ws + WS_S);
  short* w1t  = (short*)(ws + WS_W1T);
  short* w2t  = (short*)(ws + WS_W2T);
  short* w3t  = (short*)(ws + WS_W3T);

  prep_state<<<dim3(512), dim3(256), 0, stream>>>(ec3_last, ec5_last, flags,
                                                  (unsigned*)ec3s, ec5f, ec3f);
  prep_wt<<<dim3(1024), dim3(256), 0, stream>>>(wec3ca1, wca1ec5, w1t, w2t);
  prep_w3<<<dim3(4096), dim3(256), 0, stream>>>(inter_w, w3t);
  prep_ca3<<<dim3(1024), dim3(256), 0, stream>>>(wca3ca1, stab);

  hipFuncSetAttribute((const void*)stepchunk,
                      hipFuncAttributeMaxDynamicSharedMemorySize, 98304);

  for (int c = 0; c < Tn / CHUNK; ++c) {
    stepchunk<<<dim3(128), dim3(256), 98304, stream>>>(
        cue, w1t, w2t, w3t, stab, ca1bias, ec5bias, inter_b,
        flags, ec3s, ca1s, ec5f, ec3f, ca1l, out, c * CHUNK);
  }

  act_cell<<<dim3(1), dim3(128), 0, stream>>>(ca1l, wca1act, actbias, out);
}

// Round 11
// 8191.415 us; speedup vs baseline: 3.3550x; 1.0944x over previous
//
#include <hip/hip_runtime.h>

#define Lnum 2
#define BSn  64
#define Tn   512
#define ECn  1024
#define CA1n 1024
#define CHUNK 16

typedef short bf16x8 __attribute__((ext_vector_type(8)));
typedef float f32x4  __attribute__((ext_vector_type(4)));

#define MFMA16(a,b,c) __builtin_amdgcn_mfma_f32_16x16x32_bf16((a),(b),(c),0,0,0)

// d_out layout: [actCell 64*2][ec3his 2*512*1024][ec5his ...][ca1his ...]
#define OUT_E3  128
#define OUT_E5  (128 + Lnum*Tn*ECn)
#define OUT_CA1 (128 + 2*Lnum*Tn*ECn)

// ws layout (bytes)
#define WS_FLAGS 0                      // sentA[128] @ 0, sentB[128] @ +512B
#define WS_EC3S  8192                   // bf16 [16 slot][2 L][64][1024] = 4MB
#define WS_CA1S  4202496                // bf16 [16 slot][2 L][64][1024] = 4MB
#define WS_EC5F  8396800                // f32 [2][64][1024]
#define WS_EC3F  8921088                // f32 [2][64][1024]
#define WS_CA1L  9445376                // f32 [64][1024]
#define WS_S     9707520                // bf16 [2][512][1024]
#define WS_W1T   11804672               // bf16 [2][1024c][1024k]
#define WS_W2T   15998976               // bf16 [2][1024e][1024k]
#define WS_W3T   20193280               // bf16 [1024e][1024k]  (ends ~22.3MB)

#define AST(p, v) __hip_atomic_store((p), (v), __ATOMIC_RELAXED, __HIP_MEMORY_SCOPE_AGENT)
#define ALD(p)    __hip_atomic_load((p), __ATOMIC_RELAXED, __HIP_MEMORY_SCOPE_AGENT)

__device__ __forceinline__ float sigm(float x) { return 1.0f / (1.0f + __expf(-x)); }

__device__ __forceinline__ unsigned f2bfu(float f) {
  unsigned u = __float_as_uint(f);
  u += 0x7fffu + ((u >> 16) & 1u);   // RNE
  return u >> 16;
}
__device__ __forceinline__ short f2bf(float f) { return (short)f2bfu(f); }
__device__ __forceinline__ float bf2f(short s) {
  return __uint_as_float(((unsigned)(unsigned short)s) << 16);
}

// ---- dependency sentinels: WAVE-0-ONLY paced polls; parity-strided gathers ----
// layer li's 64 blocks are ids {2k+li}; gather sent[2*lane+li].
__device__ __forceinline__ void pollLayer(const unsigned* s, int li, unsigned need) {
  const int lane = threadIdx.x & 63;
  while (__any(ALD(&s[(lane << 1) | li]) < need)) __builtin_amdgcn_s_sleep(1);
  __builtin_amdgcn_sched_barrier(0);
  asm volatile("" ::: "memory");
}
__device__ __forceinline__ void pollBoth(const unsigned* s, unsigned need) {
  const int lane = threadIdx.x & 63;
  while (__any((ALD(&s[lane << 1]) < need) | (ALD(&s[(lane << 1) | 1]) < need)))
    __builtin_amdgcn_s_sleep(1);
  __builtin_amdgcn_sched_barrier(0);
  asm volatile("" ::: "memory");
}
// Publish: drain own sc1 slot stores, then tid0 posts the sentinel.
__device__ __forceinline__ void publish(unsigned* s, int bid, unsigned val) {
  asm volatile("s_waitcnt vmcnt(0)" ::: "memory");
  __syncthreads();
  if (threadIdx.x == 0) AST(&s[bid], val);
}

// ---------------- prep kernels (R4-R10 proven) ----------------

__global__ void prep_state(const float* __restrict__ ec3_last,
                           const float* __restrict__ ec5_last,
                           unsigned* __restrict__ flags, unsigned* __restrict__ ec3su,
                           float* __restrict__ ec5f, float* __restrict__ ec3f) {
  int i = blockIdx.x * blockDim.x + threadIdx.x;   // 512*256 = 131072
  if (i < 2048) flags[i] = 0u;
  float v3 = ec3_last[i];
  ec3f[i] = v3;
  ec5f[i] = ec5_last[i];
  if (i < Lnum * BSn * 512) {      // pack initial ec3 into slot 15
    float lo = ec3_last[2 * i], hi = ec3_last[2 * i + 1];
    ec3su[15 * 65536 + i] = f2bfu(lo) | (f2bfu(hi) << 16);
  }
}

// 64x64 LDS tile transpose fp32[k][c] -> bf16[c][k], for W1 (m=0) and W2 (m=1)
__global__ void prep_wt(const float* __restrict__ w1, const float* __restrict__ w2,
                        short* __restrict__ w1t, short* __restrict__ w2t) {
  __shared__ float tile[64][65];
  const int b = blockIdx.x;               // 1024 = 2 mats * 2 layers * 16*16 tiles
  const int m  = b >> 9;
  const int li = (b >> 8) & 1;
  const int kt = (b >> 4) & 15;
  const int ct = b & 15;
  const float* src = (m == 0 ? w1 : w2) + li * (1024 * 1024);
  short* dst = (m == 0 ? w1t : w2t) + li * (1024 * 1024);
#pragma unroll
  for (int i = 0; i < 16; ++i) {
    int idx = threadIdx.x + i * 256;
    int r = idx >> 6, c = idx & 63;
    tile[r][c] = src[(kt * 64 + r) * 1024 + ct * 64 + c];
  }
  __syncthreads();
#pragma unroll
  for (int i = 0; i < 16; ++i) {
    int idx = threadIdx.x + i * 256;
    int c = idx >> 6, r = idx & 63;
    dst[(ct * 64 + c) * 1024 + kt * 64 + r] = f2bf(tile[r][c]);
  }
}

__global__ void prep_w3(const float* __restrict__ inter_w, short* __restrict__ w3t) {
  int i = blockIdx.x * blockDim.x + threadIdx.x;   // 4096*256 = 1048576
  w3t[i] = f2bf(inter_w[i]);                        // layer 0, already [e][k]
}

__global__ void prep_ca3(const float* __restrict__ wca3ca1, short* __restrict__ S) {
  const int t = blockIdx.x >> 1, li = blockIdx.x & 1;
  __shared__ float gauss[192];
  const float stepc = 512.0f / 1023.0f;
  const float tf = (float)t;
  int kmin = (int)floorf((tf - 40.0f) / stepc) - 1; if (kmin < 0) kmin = 0;
  int kmax = (int)ceilf((tf + 40.0f) / stepc) + 1;  if (kmax > 1023) kmax = 1023;
  int nw = kmax - kmin + 1;
  for (int j = threadIdx.x; j < nw; j += 256) {
    float d = (float)(kmin + j) * stepc - tf;
    gauss[j] = __expf(-d * d * 0.02f);
  }
  __syncthreads();
  const float* W = wca3ca1 + li * (1024 * 1024);
  for (int c = threadIdx.x; c < 1024; c += 256) {
    float s = 0.0f;
    for (int j = 0; j < nw; ++j) s += gauss[j] * W[(kmin + j) * 1024 + c];
    S[(li * Tn + t) * 1024 + c] = f2bf(sigm(10.0f * (s - 0.5f)));
  }
}

// ---------------- 16-step chunk kernel ----------------
// grid 128, block 256 = 4 waves. XCD-SEGREGATED layer mapping: li = b&1 so
// (with round-robin b%8 XCD dispatch) layer-0 lives on even XCDs, layer-1 on
// odd XCDs -> each layer's activation panels are demand-fetched by only 4 XCDs
// instead of 8, cutting coherence-point traffic ~40%.
__global__ void __launch_bounds__(256, 1) stepchunk(
    const float* __restrict__ cue,
    const short* __restrict__ w1t, const short* __restrict__ w2t,
    const short* __restrict__ w3t, const short* __restrict__ stab,
    const float* __restrict__ ca1bias, const float* __restrict__ ec5bias,
    const float* __restrict__ interb,
    unsigned* __restrict__ flags, short* __restrict__ ec3s,
    short* __restrict__ ca1s, float* __restrict__ ec5f, float* __restrict__ ec3f,
    float* __restrict__ ca1l, float* __restrict__ out, int t0) {
  extern __shared__ short lds[];
  short* BT1 = lds;             // [16c][1024k] swizzled: idx = c*1024 + (k ^ ((c&7)<<3))
  short* BT2 = lds + 16 * 1024;
  short* BT3 = lds + 32 * 1024;

  unsigned* sentA = flags;          // [128]
  unsigned* sentB = flags + 128;    // [128]
  unsigned* ec3su = (unsigned*)ec3s;
  unsigned* ca1su = (unsigned*)ca1s;

  const int b = blockIdx.x;
  const int li = b & 1;              // XCD-segregated layer mapping
  const int c0 = (b >> 1) << 4;      // column tile start (16 cols)
  const int tid = threadIdx.x;
  const int lane = tid & 63, wave = tid >> 6;
  const int fr = lane & 15, ks = lane >> 4;
  const int r0 = wave << 4;
  const int ccol = c0 + fr;

  // ---- stage weight slices into LDS once per chunk
  {
    int cp = tid & 15;
    int k0 = (tid >> 4) << 6;
    int xm = (cp & 7) << 3;
    const short* s1 = w1t + li * 1048576 + (c0 + cp) * 1024;
    const short* s2 = w2t + li * 1048576 + (c0 + cp) * 1024;
#pragma unroll
    for (int j = 0; j < 8; ++j) {
      int k = k0 + j * 8;
      *(bf16x8*)(BT1 + cp * 1024 + (k ^ xm)) = *(const bf16x8*)(s1 + k);
      *(bf16x8*)(BT2 + cp * 1024 + (k ^ xm)) = *(const bf16x8*)(s2 + k);
    }
    if (li == 1) {
      const short* s3 = w3t + (c0 + cp) * 1024;
#pragma unroll
      for (int j = 0; j < 8; ++j) {
        int k = k0 + j * 8;
        *(bf16x8*)(BT3 + cp * 1024 + (k ^ xm)) = *(const bf16x8*)(s3 + k);
      }
    }
  }
  __syncthreads();

  const int xsw = (fr & 7) << 3;
  const short* B1 = BT1 + fr * 1024;
  const short* B2 = BT2 + fr * 1024;
  const short* B3 = BT3 + fr * 1024;

  const float cb  = ca1bias[li * 1024 + ccol];
  const float e5b = ec5bias[li * 1024 + ccol];
  const float ib0 = interb[1024 + ccol];    // layer-1 inter_b (used when li==1)

  // block-exclusive fp32 state -> registers for the chunk
  float e5r[4], e3r[4];
#pragma unroll
  for (int r = 0; r < 4; ++r) {
    int sidx = li * 65536 + (r0 + ks * 4 + r) * 1024 + ccol;
    e5r[r] = ec5f[sidx];
    e3r[r] = ec3f[sidx];
  }

  bf16x8 ar[32], ar3[32];

  for (int tt = 0; tt < CHUNK; ++tt) {
    const int t = t0 + tt;
    const int rd = (tt + 15) & 15;   // ec3 slot written last step (15 = initial/prev)

    // ---------- phase A: ca1 = relu(S * (1 + 3*sig(ec3@W1)) - bias) ----------
    f32x4 cvv;
    {
      if (wave == 0) pollLayer(sentB, li, (unsigned)t);
      __syncthreads();
      const short* A1 = ec3s + ((rd * 2 + li) * 64 + (r0 + fr)) * 1024 + ks * 8;
#pragma unroll
      for (int kk = 0; kk < 16; ++kk) {
        ar[kk]      = *(const bf16x8*)(A1 + kk * 32);
        ar[16 + kk] = *(const bf16x8*)(A1 + 512 + kk * 32);
      }
      __builtin_amdgcn_sched_barrier(0);   // bulk-issue all 32 loads first
      f32x4 a0 = {0.f,0.f,0.f,0.f}, a1 = {0.f,0.f,0.f,0.f};
#pragma unroll
      for (int kk = 0; kk < 16; ++kk) {
        a0 = MFMA16(ar[kk],      *(const bf16x8*)(B1 + ((kk * 32 + ks * 8) ^ xsw)),       a0);
        a1 = MFMA16(ar[16 + kk], *(const bf16x8*)(B1 + ((512 + kk * 32 + ks * 8) ^ xsw)), a1);
      }
      f32x4 acc = a0 + a1;
      const float g = bf2f(stab[(li * Tn + t) * 1024 + ccol]);
#pragma unroll
      for (int r = 0; r < 4; ++r) {
        int grow = r0 + ks * 4 + r;
        float cv = fmaxf(g * (1.0f + 3.0f * sigm(acc[r])) - cb, 0.0f);
        cvv[r] = cv;
        unsigned my = f2bfu(cv);
        unsigned pr = (unsigned)__shfl_xor((int)my, 1);
        if ((fr & 1) == 0)
          AST(ca1su + ((tt * 2 + li) * 64 + grow) * 512 + ((c0 + fr) >> 1), my | (pr << 16));
      }
      publish(sentA, b, (unsigned)(t + 1));   // drain covers ONLY slot stores
      // deferred history writes (off the publish critical path)
#pragma unroll
      for (int r = 0; r < 4; ++r) {
        int grow = r0 + ks * 4 + r;
        if (grow == 0) out[OUT_CA1 + (li * Tn + t) * 1024 + ccol] = cvv[r];
        if (t == Tn - 1 && li == 1) ca1l[grow * 1024 + ccol] = cvv[r];
      }
    }

    // ---------- phase B: ec5/ec3 update ----------
    {
      float cueq[4];
      if (li == 0) {                       // prefetch cue NOW (overlaps the poll)
#pragma unroll
        for (int r = 0; r < 4; ++r)
          cueq[r] = cue[((r0 + ks * 4 + r) * Tn + t) * 1024 + ccol];
      }
      if (wave == 0) {
        if (li == 0) pollLayer(sentA, 0, (unsigned)(t + 1));
        else         pollBoth(sentA, (unsigned)(t + 1));
      }
      __syncthreads();
      const short* A2 = ca1s + ((tt * 2 + li) * 64 + (r0 + fr)) * 1024 + ks * 8;
#pragma unroll
      for (int kk = 0; kk < 16; ++kk) {
        ar[kk]      = *(const bf16x8*)(A2 + kk * 32);
        ar[16 + kk] = *(const bf16x8*)(A2 + 512 + kk * 32);
      }
      if (li == 1) {                       // also bulk-issue the G3 panel loads
        const short* A3 = ca1s + ((tt * 2) * 64 + (r0 + fr)) * 1024 + ks * 8;
#pragma unroll
        for (int kk = 0; kk < 16; ++kk) {
          ar3[kk]      = *(const bf16x8*)(A3 + kk * 32);
          ar3[16 + kk] = *(const bf16x8*)(A3 + 512 + kk * 32);
        }
      }
      __builtin_amdgcn_sched_barrier(0);
      f32x4 p0 = {0.f,0.f,0.f,0.f}, p1 = {0.f,0.f,0.f,0.f};
#pragma unroll
      for (int kk = 0; kk < 16; ++kk) {
        p0 = MFMA16(ar[kk],      *(const bf16x8*)(B2 + ((kk * 32 + ks * 8) ^ xsw)),       p0);
        p1 = MFMA16(ar[16 + kk], *(const bf16x8*)(B2 + ((512 + kk * 32 + ks * 8) ^ xsw)), p1);
      }
      f32x4 g2 = p0 + p1;

      f32x4 xin;
      if (li == 1) {
        f32x4 q0 = {0.f,0.f,0.f,0.f}, q1 = {0.f,0.f,0.f,0.f};
#pragma unroll
        for (int kk = 0; kk < 16; ++kk) {
          q0 = MFMA16(ar3[kk],      *(const bf16x8*)(B3 + ((kk * 32 + ks * 8) ^ xsw)),       q0);
          q1 = MFMA16(ar3[16 + kk], *(const bf16x8*)(B3 + ((512 + kk * 32 + ks * 8) ^ xsw)), q1);
        }
        f32x4 q = q0 + q1;
#pragma unroll
        for (int r = 0; r < 4; ++r) xin[r] = q[r] + ib0;
      } else {
#pragma unroll
        for (int r = 0; r < 4; ++r) xin[r] = cueq[r];
      }

#pragma unroll
      for (int r = 0; r < 4; ++r) {
        float raw = e5r[r] + g2[r] + e5b;            // 10*TS == 1.0f exactly
        float e5 = 0.69f + 0.3f * sigm(4.0f * (raw - 0.3f));
        e5r[r] = e5;
        float e3 = e5 * e3r[r] + 0.6f * xin[r];
        e3r[r] = e3;
        int grow = r0 + ks * 4 + r;
        unsigned my = f2bfu(e3);
        unsigned pr = (unsigned)__shfl_xor((int)my, 1);
        if ((fr & 1) == 0)
          AST(ec3su + ((tt * 2 + li) * 64 + grow) * 512 + ((c0 + fr) >> 1), my | (pr << 16));
      }
      publish(sentB, b, (unsigned)(t + 1));   // drain covers ONLY slot stores
      // deferred history writes
#pragma unroll
      for (int r = 0; r < 4; ++r) {
        int grow = r0 + ks * 4 + r;
        if (grow == 0) {
          out[OUT_E5 + (li * Tn + t) * 1024 + ccol] = e5r[r];
          out[OUT_E3 + (li * Tn + t) * 1024 + ccol] = e3r[r];
        }
      }
    }
  }

  // spill fp32 state for next chunk (dispatch boundary provides coherence)
#pragma unroll
  for (int r = 0; r < 4; ++r) {
    int sidx = li * 65536 + (r0 + ks * 4 + r) * 1024 + ccol;
    ec5f[sidx] = e5r[r];
    ec3f[sidx] = e3r[r];
  }
}

__global__ void act_cell(const float* __restrict__ ca1l, const float* __restrict__ wca1act,
                         const float* __restrict__ actbias, float* __restrict__ out) {
  int tid = threadIdx.x;
  if (tid < 128) {
    int b = tid >> 1, a = tid & 1;
    float s = 0.0f;
    for (int k = 0; k < 1024; ++k) s += ca1l[b * 1024 + k] * wca1act[k * 2 + a];
    out[b * 2 + a] = s + actbias[a];
  }
}

extern "C" void kernel_launch(void* const* d_in, const int* in_sizes, int n_in,
                              void* d_out, int out_size, void* d_ws, size_t ws_size,
                              hipStream_t stream) {
  (void)in_sizes; (void)n_in; (void)out_size; (void)ws_size;
  const float* cue      = (const float*)d_in[0];
  const float* ec3_last = (const float*)d_in[1];
  const float* ec5_last = (const float*)d_in[2];
  const float* wca3ca1  = (const float*)d_in[4];
  const float* wec3ca1  = (const float*)d_in[5];
  const float* wca1ec5  = (const float*)d_in[6];
  const float* ca1bias  = (const float*)d_in[7];
  const float* ec5bias  = (const float*)d_in[8];
  const float* inter_w  = (const float*)d_in[9];
  const float* inter_b  = (const float*)d_in[10];
  const float* wca1act  = (const float*)d_in[11];
  const float* actbias  = (const float*)d_in[12];
  float* out = (float*)d_out;

  char* ws = (char*)d_ws;
  unsigned* flags = (unsigned*)(ws + WS_FLAGS);
  short* ec3s = (short*)(ws + WS_EC3S);
  short* ca1s = (short*)(ws + WS_CA1S);
  float* ec5f = (float*)(ws + WS_EC5F);
  float* ec3f = (float*)(ws + WS_EC3F);
  float* ca1l = (float*)(ws + WS_CA1L);
  short* stab = (short*)(ws + WS_S);
  short* w1t  = (short*)(ws + WS_W1T);
  short* w2t  = (short*)(ws + WS_W2T);
  short* w3t  = (short*)(ws + WS_W3T);

  prep_state<<<dim3(512), dim3(256), 0, stream>>>(ec3_last, ec5_last, flags,
                                                  (unsigned*)ec3s, ec5f, ec3f);
  prep_wt<<<dim3(1024), dim3(256), 0, stream>>>(wec3ca1, wca1ec5, w1t, w2t);
  prep_w3<<<dim3(4096), dim3(256), 0, stream>>>(inter_w, w3t);
  prep_ca3<<<dim3(1024), dim3(256), 0, stream>>>(wca3ca1, stab);

  hipFuncSetAttribute((const void*)stepchunk,
                      hipFuncAttributeMaxDynamicSharedMemorySize, 98304);

  for (int c = 0; c < Tn / CHUNK; ++c) {
    stepchunk<<<dim3(128), dim3(256), 98304, stream>>>(
        cue, w1t, w2t, w3t, stab, ca1bias, ec5bias, inter_b,
        flags, ec3s, ca1s, ec5f, ec3f, ca1l, out, c * CHUNK);
  }

  act_cell<<<dim3(1), dim3(128), 0, stream>>>(ca1l, wca1act, actbias, out);
}

// Round 12
// 8144.399 us; speedup vs baseline: 3.3744x; 1.0058x over previous
//
#include <hip/hip_runtime.h>

#define Lnum 2
#define BSn  64
#define Tn   512
#define ECn  1024
#define CA1n 1024
#define CHUNK 16

typedef short bf16x8 __attribute__((ext_vector_type(8)));
typedef float f32x4  __attribute__((ext_vector_type(4)));

#define MFMA16(a,b,c) __builtin_amdgcn_mfma_f32_16x16x32_bf16((a),(b),(c),0,0,0)

// d_out layout: [actCell 64*2][ec3his 2*512*1024][ec5his ...][ca1his ...]
#define OUT_E3  128
#define OUT_E5  (128 + Lnum*Tn*ECn)
#define OUT_CA1 (128 + 2*Lnum*Tn*ECn)

// ws layout (bytes)
#define WS_FLAGS 0                      // 4 epoch counters, one per 64B line
#define WS_EC3S  8192                   // bf16 [16 slot][2 L][64][1024] = 4MB
#define WS_CA1S  4202496                // bf16 [16 slot][2 L][64][1024] = 4MB
#define WS_EC5F  8396800                // f32 [2][64][1024]
#define WS_EC3F  8921088                // f32 [2][64][1024]
#define WS_CA1L  9445376                // f32 [64][1024]
#define WS_S     9707520                // bf16 [2][512][1024]
#define WS_W1T   11804672               // bf16 [2][1024c][1024k]
#define WS_W2T   15998976               // bf16 [2][1024e][1024k]
#define WS_W3T   20193280               // bf16 [1024e][1024k]  (ends ~22.3MB)

#define AST(p, v) __hip_atomic_store((p), (v), __ATOMIC_RELAXED, __HIP_MEMORY_SCOPE_AGENT)
#define ALD(p)    __hip_atomic_load((p), __ATOMIC_RELAXED, __HIP_MEMORY_SCOPE_AGENT)

__device__ __forceinline__ float sigm(float x) { return 1.0f / (1.0f + __expf(-x)); }

__device__ __forceinline__ unsigned f2bfu(float f) {
  unsigned u = __float_as_uint(f);
  u += 0x7fffu + ((u >> 16) & 1u);   // RNE
  return u >> 16;
}
__device__ __forceinline__ short f2bf(float f) { return (short)f2bfu(f); }
__device__ __forceinline__ float bf2f(short s) {
  return __uint_as_float(((unsigned)(unsigned short)s) << 16);
}

// ---- epoch-counter sync: 4 line-padded counters; producer atomicAdd, ------
// ---- single-word wave-0 poll (all lanes same addr -> ~1 request/round). ----
// cntA[li] = flags[li*16], cntB[li] = flags[32 + li*16]
__device__ __forceinline__ void pollCnt(const unsigned* c, unsigned need) {
  while (ALD(c) < need) __builtin_amdgcn_s_sleep(1);
  __builtin_amdgcn_sched_barrier(0);
  asm volatile("" ::: "memory");
}
__device__ __forceinline__ void pollCnt2(const unsigned* c0, const unsigned* c1,
                                         unsigned need) {
  while ((ALD(c0) < need) | (ALD(c1) < need)) __builtin_amdgcn_s_sleep(1);
  __builtin_amdgcn_sched_barrier(0);
  asm volatile("" ::: "memory");
}
// Publish: drain own sc1 slot stores, then tid0 bumps the epoch counter.
__device__ __forceinline__ void publish(unsigned* c) {
  asm volatile("s_waitcnt vmcnt(0)" ::: "memory");
  __syncthreads();
  if (threadIdx.x == 0)
    __hip_atomic_fetch_add(c, 1u, __ATOMIC_RELAXED, __HIP_MEMORY_SCOPE_AGENT);
}

// ---------------- prep kernels (R4-R11 proven) ----------------

__global__ void prep_state(const float* __restrict__ ec3_last,
                           const float* __restrict__ ec5_last,
                           unsigned* __restrict__ flags, unsigned* __restrict__ ec3su,
                           float* __restrict__ ec5f, float* __restrict__ ec3f) {
  int i = blockIdx.x * blockDim.x + threadIdx.x;   // 512*256 = 131072
  if (i < 2048) flags[i] = 0u;
  float v3 = ec3_last[i];
  ec3f[i] = v3;
  ec5f[i] = ec5_last[i];
  if (i < Lnum * BSn * 512) {      // pack initial ec3 into slot 15
    float lo = ec3_last[2 * i], hi = ec3_last[2 * i + 1];
    ec3su[15 * 65536 + i] = f2bfu(lo) | (f2bfu(hi) << 16);
  }
}

// 64x64 LDS tile transpose fp32[k][c] -> bf16[c][k], for W1 (m=0) and W2 (m=1)
__global__ void prep_wt(const float* __restrict__ w1, const float* __restrict__ w2,
                        short* __restrict__ w1t, short* __restrict__ w2t) {
  __shared__ float tile[64][65];
  const int b = blockIdx.x;               // 1024 = 2 mats * 2 layers * 16*16 tiles
  const int m  = b >> 9;
  const int li = (b >> 8) & 1;
  const int kt = (b >> 4) & 15;
  const int ct = b & 15;
  const float* src = (m == 0 ? w1 : w2) + li * (1024 * 1024);
  short* dst = (m == 0 ? w1t : w2t) + li * (1024 * 1024);
#pragma unroll
  for (int i = 0; i < 16; ++i) {
    int idx = threadIdx.x + i * 256;
    int r = idx >> 6, c = idx & 63;
    tile[r][c] = src[(kt * 64 + r) * 1024 + ct * 64 + c];
  }
  __syncthreads();
#pragma unroll
  for (int i = 0; i < 16; ++i) {
    int idx = threadIdx.x + i * 256;
    int c = idx >> 6, r = idx & 63;
    dst[(ct * 64 + c) * 1024 + kt * 64 + r] = f2bf(tile[r][c]);
  }
}

__global__ void prep_w3(const float* __restrict__ inter_w, short* __restrict__ w3t) {
  int i = blockIdx.x * blockDim.x + threadIdx.x;   // 4096*256 = 1048576
  w3t[i] = f2bf(inter_w[i]);                        // layer 0, already [e][k]
}

__global__ void prep_ca3(const float* __restrict__ wca3ca1, short* __restrict__ S) {
  const int t = blockIdx.x >> 1, li = blockIdx.x & 1;
  __shared__ float gauss[192];
  const float stepc = 512.0f / 1023.0f;
  const float tf = (float)t;
  int kmin = (int)floorf((tf - 40.0f) / stepc) - 1; if (kmin < 0) kmin = 0;
  int kmax = (int)ceilf((tf + 40.0f) / stepc) + 1;  if (kmax > 1023) kmax = 1023;
  int nw = kmax - kmin + 1;
  for (int j = threadIdx.x; j < nw; j += 256) {
    float d = (float)(kmin + j) * stepc - tf;
    gauss[j] = __expf(-d * d * 0.02f);
  }
  __syncthreads();
  const float* W = wca3ca1 + li * (1024 * 1024);
  for (int c = threadIdx.x; c < 1024; c += 256) {
    float s = 0.0f;
    for (int j = 0; j < nw; ++j) s += gauss[j] * W[(kmin + j) * 1024 + c];
    S[(li * Tn + t) * 1024 + c] = f2bf(sigm(10.0f * (s - 0.5f)));
  }
}

// ---------------- 16-step chunk kernel ----------------
// grid 128, block 256 = 4 waves. XCD-segregated layers (li = b&1, R11-proven).
// Sync: 4 line-padded epoch counters; producers atomicAdd after drain,
// consumers poll one word (two for l1 phase B). No hot-line gather storms.
__global__ void __launch_bounds__(256, 1) stepchunk(
    const float* __restrict__ cue,
    const short* __restrict__ w1t, const short* __restrict__ w2t,
    const short* __restrict__ w3t, const short* __restrict__ stab,
    const float* __restrict__ ca1bias, const float* __restrict__ ec5bias,
    const float* __restrict__ interb,
    unsigned* __restrict__ flags, short* __restrict__ ec3s,
    short* __restrict__ ca1s, float* __restrict__ ec5f, float* __restrict__ ec3f,
    float* __restrict__ ca1l, float* __restrict__ out, int t0) {
  extern __shared__ short lds[];
  short* BT1 = lds;             // [16c][1024k] swizzled: idx = c*1024 + (k ^ ((c&7)<<3))
  short* BT2 = lds + 16 * 1024;
  short* BT3 = lds + 32 * 1024;

  unsigned* cntA0 = flags;            // layer-0 phase-A arrivals (line 0)
  unsigned* cntA1 = flags + 16;       // layer-1 phase-A arrivals (line 1)
  unsigned* cntB0 = flags + 32;       // layer-0 phase-B arrivals (line 2)
  unsigned* cntB1 = flags + 48;       // layer-1 phase-B arrivals (line 3)
  unsigned* ec3su = (unsigned*)ec3s;
  unsigned* ca1su = (unsigned*)ca1s;

  const int b = blockIdx.x;
  const int li = b & 1;              // XCD-segregated layer mapping
  const int c0 = (b >> 1) << 4;      // column tile start (16 cols)
  const int tid = threadIdx.x;
  const int lane = tid & 63, wave = tid >> 6;
  const int fr = lane & 15, ks = lane >> 4;
  const int r0 = wave << 4;
  const int ccol = c0 + fr;

  unsigned* myCntA = li ? cntA1 : cntA0;
  unsigned* myCntB = li ? cntB1 : cntB0;

  // ---- stage weight slices into LDS once per chunk
  {
    int cp = tid & 15;
    int k0 = (tid >> 4) << 6;
    int xm = (cp & 7) << 3;
    const short* s1 = w1t + li * 1048576 + (c0 + cp) * 1024;
    const short* s2 = w2t + li * 1048576 + (c0 + cp) * 1024;
#pragma unroll
    for (int j = 0; j < 8; ++j) {
      int k = k0 + j * 8;
      *(bf16x8*)(BT1 + cp * 1024 + (k ^ xm)) = *(const bf16x8*)(s1 + k);
      *(bf16x8*)(BT2 + cp * 1024 + (k ^ xm)) = *(const bf16x8*)(s2 + k);
    }
    if (li == 1) {
      const short* s3 = w3t + (c0 + cp) * 1024;
#pragma unroll
      for (int j = 0; j < 8; ++j) {
        int k = k0 + j * 8;
        *(bf16x8*)(BT3 + cp * 1024 + (k ^ xm)) = *(const bf16x8*)(s3 + k);
      }
    }
  }
  __syncthreads();

  const int xsw = (fr & 7) << 3;
  const short* B1 = BT1 + fr * 1024;
  const short* B2 = BT2 + fr * 1024;
  const short* B3 = BT3 + fr * 1024;

  const float cb  = ca1bias[li * 1024 + ccol];
  const float e5b = ec5bias[li * 1024 + ccol];
  const float ib0 = interb[1024 + ccol];    // layer-1 inter_b (used when li==1)

  // block-exclusive fp32 state -> registers for the chunk
  float e5r[4], e3r[4];
#pragma unroll
  for (int r = 0; r < 4; ++r) {
    int sidx = li * 65536 + (r0 + ks * 4 + r) * 1024 + ccol;
    e5r[r] = ec5f[sidx];
    e3r[r] = ec3f[sidx];
  }

  bf16x8 ar[32], ar3[32];

  for (int tt = 0; tt < CHUNK; ++tt) {
    const int t = t0 + tt;
    const int rd = (tt + 15) & 15;   // ec3 slot written last step (15 = initial/prev)

    // ---------- phase A: ca1 = relu(S * (1 + 3*sig(ec3@W1)) - bias) ----------
    f32x4 cvv;
    {
      if (wave == 0) pollCnt(myCntB, 64u * (unsigned)t);   // own layer ec3[t-1]
      __syncthreads();
      const short* A1 = ec3s + ((rd * 2 + li) * 64 + (r0 + fr)) * 1024 + ks * 8;
#pragma unroll
      for (int kk = 0; kk < 16; ++kk) {
        ar[kk]      = *(const bf16x8*)(A1 + kk * 32);
        ar[16 + kk] = *(const bf16x8*)(A1 + 512 + kk * 32);
      }
      __builtin_amdgcn_sched_barrier(0);   // bulk-issue all 32 loads first
      f32x4 a0 = {0.f,0.f,0.f,0.f}, a1 = {0.f,0.f,0.f,0.f};
#pragma unroll
      for (int kk = 0; kk < 16; ++kk) {
        a0 = MFMA16(ar[kk],      *(const bf16x8*)(B1 + ((kk * 32 + ks * 8) ^ xsw)),       a0);
        a1 = MFMA16(ar[16 + kk], *(const bf16x8*)(B1 + ((512 + kk * 32 + ks * 8) ^ xsw)), a1);
      }
      f32x4 acc = a0 + a1;
      const float g = bf2f(stab[(li * Tn + t) * 1024 + ccol]);
#pragma unroll
      for (int r = 0; r < 4; ++r) {
        int grow = r0 + ks * 4 + r;
        float cv = fmaxf(g * (1.0f + 3.0f * sigm(acc[r])) - cb, 0.0f);
        cvv[r] = cv;
        unsigned my = f2bfu(cv);
        unsigned pr = (unsigned)__shfl_xor((int)my, 1);
        if ((fr & 1) == 0)
          AST(ca1su + ((tt * 2 + li) * 64 + grow) * 512 + ((c0 + fr) >> 1), my | (pr << 16));
      }
      publish(myCntA);                     // drain covers ONLY slot stores
      // deferred history writes (off the publish critical path)
#pragma unroll
      for (int r = 0; r < 4; ++r) {
        int grow = r0 + ks * 4 + r;
        if (grow == 0) out[OUT_CA1 + (li * Tn + t) * 1024 + ccol] = cvv[r];
        if (t == Tn - 1 && li == 1) ca1l[grow * 1024 + ccol] = cvv[r];
      }
    }

    // ---------- phase B: ec5/ec3 update ----------
    {
      float cueq[4];
      if (li == 0) {                       // prefetch cue NOW (overlaps the poll)
#pragma unroll
        for (int r = 0; r < 4; ++r)
          cueq[r] = cue[((r0 + ks * 4 + r) * Tn + t) * 1024 + ccol];
      }
      if (wave == 0) {
        if (li == 0) pollCnt(cntA0, 64u * (unsigned)(t + 1));
        else         pollCnt2(cntA0, cntA1, 64u * (unsigned)(t + 1));
      }
      __syncthreads();
      const short* A2 = ca1s + ((tt * 2 + li) * 64 + (r0 + fr)) * 1024 + ks * 8;
#pragma unroll
      for (int kk = 0; kk < 16; ++kk) {
        ar[kk]      = *(const bf16x8*)(A2 + kk * 32);
        ar[16 + kk] = *(const bf16x8*)(A2 + 512 + kk * 32);
      }
      if (li == 1) {                       // also bulk-issue the G3 panel loads
        const short* A3 = ca1s + ((tt * 2) * 64 + (r0 + fr)) * 1024 + ks * 8;
#pragma unroll
        for (int kk = 0; kk < 16; ++kk) {
          ar3[kk]      = *(const bf16x8*)(A3 + kk * 32);
          ar3[16 + kk] = *(const bf16x8*)(A3 + 512 + kk * 32);
        }
      }
      __builtin_amdgcn_sched_barrier(0);
      f32x4 p0 = {0.f,0.f,0.f,0.f}, p1 = {0.f,0.f,0.f,0.f};
#pragma unroll
      for (int kk = 0; kk < 16; ++kk) {
        p0 = MFMA16(ar[kk],      *(const bf16x8*)(B2 + ((kk * 32 + ks * 8) ^ xsw)),       p0);
        p1 = MFMA16(ar[16 + kk], *(const bf16x8*)(B2 + ((512 + kk * 32 + ks * 8) ^ xsw)), p1);
      }
      f32x4 g2 = p0 + p1;

      f32x4 xin;
      if (li == 1) {
        f32x4 q0 = {0.f,0.f,0.f,0.f}, q1 = {0.f,0.f,0.f,0.f};
#pragma unroll
        for (int kk = 0; kk < 16; ++kk) {
          q0 = MFMA16(ar3[kk],      *(const bf16x8*)(B3 + ((kk * 32 + ks * 8) ^ xsw)),       q0);
          q1 = MFMA16(ar3[16 + kk], *(const bf16x8*)(B3 + ((512 + kk * 32 + ks * 8) ^ xsw)), q1);
        }
        f32x4 q = q0 + q1;
#pragma unroll
        for (int r = 0; r < 4; ++r) xin[r] = q[r] + ib0;
      } else {
#pragma unroll
        for (int r = 0; r < 4; ++r) xin[r] = cueq[r];
      }

#pragma unroll
      for (int r = 0; r < 4; ++r) {
        float raw = e5r[r] + g2[r] + e5b;            // 10*TS == 1.0f exactly
        float e5 = 0.69f + 0.3f * sigm(4.0f * (raw - 0.3f));
        e5r[r] = e5;
        float e3 = e5 * e3r[r] + 0.6f * xin[r];
        e3r[r] = e3;
        int grow = r0 + ks * 4 + r;
        unsigned my = f2bfu(e3);
        unsigned pr = (unsigned)__shfl_xor((int)my, 1);
        if ((fr & 1) == 0)
          AST(ec3su + ((tt * 2 + li) * 64 + grow) * 512 + ((c0 + fr) >> 1), my | (pr << 16));
      }
      publish(myCntB);                     // drain covers ONLY slot stores
      // deferred history writes
#pragma unroll
      for (int r = 0; r < 4; ++r) {
        int grow = r0 + ks * 4 + r;
        if (grow == 0) {
          out[OUT_E5 + (li * Tn + t) * 1024 + ccol] = e5r[r];
          out[OUT_E3 + (li * Tn + t) * 1024 + ccol] = e3r[r];
        }
      }
    }
  }

  // spill fp32 state for next chunk (dispatch boundary provides coherence)
#pragma unroll
  for (int r = 0; r < 4; ++r) {
    int sidx = li * 65536 + (r0 + ks * 4 + r) * 1024 + ccol;
    ec5f[sidx] = e5r[r];
    ec3f[sidx] = e3r[r];
  }
}

__global__ void act_cell(const float* __restrict__ ca1l, const float* __restrict__ wca1act,
                         const float* __restrict__ actbias, float* __restrict__ out) {
  int tid = threadIdx.x;
  if (tid < 128) {
    int b = tid >> 1, a = tid & 1;
    float s = 0.0f;
    for (int k = 0; k < 1024; ++k) s += ca1l[b * 1024 + k] * wca1act[k * 2 + a];
    out[b * 2 + a] = s + actbias[a];
  }
}

extern "C" void kernel_launch(void* const* d_in, const int* in_sizes, int n_in,
                              void* d_out, int out_size, void* d_ws, size_t ws_size,
                              hipStream_t stream) {
  (void)in_sizes; (void)n_in; (void)out_size; (void)ws_size;
  const float* cue      = (const float*)d_in[0];
  const float* ec3_last = (const float*)d_in[1];
  const float* ec5_last = (const float*)d_in[2];
  const float* wca3ca1  = (const float*)d_in[4];
  const float* wec3ca1  = (const float*)d_in[5];
  const float* wca1ec5  = (const float*)d_in[6];
  const float* ca1bias  = (const float*)d_in[7];
  const float* ec5bias  = (const float*)d_in[8];
  const float* inter_w  = (const float*)d_in[9];
  const float* inter_b  = (const float*)d_in[10];
  const float* wca1act  = (const float*)d_in[11];
  const float* actbias  = (const float*)d_in[12];
  float* out = (float*)d_out;

  char* ws = (char*)d_ws;
  unsigned* flags = (unsigned*)(ws + WS_FLAGS);
  short* ec3s = (short*)(ws + WS_EC3S);
  short* ca1s = (short*)(ws + WS_CA1S);
  float* ec5f = (float*)(ws + WS_EC5F);
  float* ec3f = (float*)(ws + WS_EC3F);
  float* ca1l = (float*)(ws + WS_CA1L);
  short* stab = (short*)(ws + WS_S);
  short* w1t  = (short*)(ws + WS_W1T);
  short* w2t  = (short*)(ws + WS_W2T);
  short* w3t  = (short*)(ws + WS_W3T);

  prep_state<<<dim3(512), dim3(256), 0, stream>>>(ec3_last, ec5_last, flags,
                                                  (unsigned*)ec3s, ec5f, ec3f);
  prep_wt<<<dim3(1024), dim3(256), 0, stream>>>(wec3ca1, wca1ec5, w1t, w2t);
  prep_w3<<<dim3(4096), dim3(256), 0, stream>>>(inter_w, w3t);
  prep_ca3<<<dim3(1024), dim3(256), 0, stream>>>(wca3ca1, stab);

  hipFuncSetAttribute((const void*)stepchunk,
                      hipFuncAttributeMaxDynamicSharedMemorySize, 98304);

  for (int c = 0; c < Tn / CHUNK; ++c) {
    stepchunk<<<dim3(128), dim3(256), 98304, stream>>>(
        cue, w1t, w2t, w3t, stab, ca1bias, ec5bias, inter_b,
        flags, ec3s, ca1s, ec5f, ec3f, ca1l, out, c * CHUNK);
  }

  act_cell<<<dim3(1), dim3(128), 0, stream>>>(ca1l, wca1act, actbias, out);
}